// Round 1
// baseline (2066.166 us; speedup 1.0000x reference)
//
#include <hip/hip_runtime.h>
#include <stdint.h>

#define NTOK 8192
#define HID 2048
#define NE 32
#define DFF 768
#define NSLOT 65536
#define NB 256
#define MT 128
#define MAX_TILES 544   // 65536/128 + 32

typedef unsigned short u16;
typedef unsigned int u32;

using f32x4 = __attribute__((ext_vector_type(4))) float;
using bf16x8 = __attribute__((ext_vector_type(8))) short;

static __device__ __forceinline__ u16 f2bf(float f) {
  u32 x = __float_as_uint(f);
  x += 0x7fffu + ((x >> 16) & 1u);
  return (u16)(x >> 16);
}

// ---------------- x -> bf16 ----------------
__global__ void convert_x_kernel(const float* __restrict__ x, u16* __restrict__ xb, int n4) {
  int i = blockIdx.x * blockDim.x + threadIdx.x;
  int stride = gridDim.x * blockDim.x;
  for (; i < n4; i += stride) {
    float4 v = reinterpret_cast<const float4*>(x)[i];
    u32 lo = (u32)f2bf(v.x) | ((u32)f2bf(v.y) << 16);
    u32 hi = (u32)f2bf(v.z) | ((u32)f2bf(v.w) << 16);
    reinterpret_cast<uint2*>(xb)[i] = make_uint2(lo, hi);
  }
}

// ---------------- router: logits + softmax + top8 + reroute ----------------
__global__ void router_kernel(const float* __restrict__ x, const float* __restrict__ gw,
                              const float* __restrict__ sim,
                              int* __restrict__ slot_e, float* __restrict__ slot_w) {
  int t = blockIdx.x;
  __shared__ float xs[HID];
  __shared__ float logits[NE];
  const float* xr = x + (size_t)t * HID;
  for (int i = threadIdx.x; i < HID / 4; i += 256)
    reinterpret_cast<float4*>(xs)[i] = reinterpret_cast<const float4*>(xr)[i];
  __syncthreads();
  int e = threadIdx.x >> 3, part = threadIdx.x & 7;
  const float4* wv = reinterpret_cast<const float4*>(gw + (size_t)e * HID + part * 256);
  const float4* xv = reinterpret_cast<const float4*>(xs + part * 256);
  float s = 0.f;
#pragma unroll
  for (int j = 0; j < 64; ++j) {
    float4 a = xv[j], b = wv[j];
    s += a.x * b.x + a.y * b.y + a.z * b.z + a.w * b.w;
  }
  s += __shfl_xor(s, 1); s += __shfl_xor(s, 2); s += __shfl_xor(s, 4);
  if (part == 0) logits[e] = s;
  __syncthreads();
  if (threadIdx.x == 0) {
    float l[NE];
#pragma unroll
    for (int i = 0; i < NE; ++i) l[i] = logits[i];
    // top-8 by logit (monotonic with softmax prob); first-max on ties like lax.top_k
    unsigned mask = 0;
    int idx[8]; float lv[8];
#pragma unroll
    for (int k = 0; k < 8; ++k) {
      float best = -3.4e38f; int bi = 0;
#pragma unroll
      for (int i = 0; i < NE; ++i) {
        bool ok = (((mask >> i) & 1u) == 0u) && (l[i] > best);
        best = ok ? l[i] : best;
        bi = ok ? i : bi;
      }
      idx[k] = bi; lv[k] = best; mask |= (1u << bi);
    }
    // weights = exp ratios over the top-8 (== topv/sum(topv) of softmax)
    float w[8]; float ssum = 0.f;
#pragma unroll
    for (int k = 0; k < 8; ++k) { w[k] = __expf(lv[k] - lv[0]); ssum += w[k]; }
    float inv = 1.f / ssum;
    int base = t * 8;
#pragma unroll
    for (int i = 0; i < 4; ++i) { slot_e[base + i] = idx[i]; slot_w[base + i] = w[i] * inv; }
#pragma unroll
    for (int j = 0; j < 4; ++j) {
      int sj = idx[4 + j];
      float best = -2.f; int bsel = idx[0];
#pragma unroll
      for (int i = 0; i < 4; ++i) {
        int pe = idx[i];
        float sv = sim[sj * NE + pe];
        bool ok = sv > best;       // strict > == argmax first-max
        best = ok ? sv : best;
        bsel = ok ? pe : bsel;
      }
      int ns = (best < 0.5f) ? sj : bsel;
      slot_e[base + 4 + j] = ns; slot_w[base + 4 + j] = w[4 + j] * inv;
    }
  }
}

// ---------------- counting sort: hist / scan / place ----------------
__global__ void hist_kernel(const int* __restrict__ slot_e, int* __restrict__ blockCounts) {
  __shared__ int cnt[NE];
  if (threadIdx.x < NE) cnt[threadIdx.x] = 0;
  __syncthreads();
  int i = blockIdx.x * 256 + threadIdx.x;
  atomicAdd(&cnt[slot_e[i]], 1);
  __syncthreads();
  if (threadIdx.x < NE) blockCounts[threadIdx.x * NB + blockIdx.x] = cnt[threadIdx.x];
}

__global__ void scan_kernel(const int* __restrict__ blockCounts, int* __restrict__ startEB,
                            int* __restrict__ tile_e, int* __restrict__ tile_row0,
                            int* __restrict__ tile_cnt, int* __restrict__ tileCount) {
  __shared__ int totals[NE];
  __shared__ int bases[NE];
  int t = threadIdx.x;
  if (t < NE) {
    int run = 0;
    for (int b = 0; b < NB; ++b) run += blockCounts[t * NB + b];
    totals[t] = run;
  }
  __syncthreads();
  if (t == 0) {
    int base = 0, nt = 0;
    for (int e = 0; e < NE; ++e) {
      bases[e] = base;
      int tot = totals[e];
      for (int i = 0; i < tot; i += MT) {
        tile_e[nt] = e;
        tile_row0[nt] = base + i;
        tile_cnt[nt] = (tot - i < MT) ? (tot - i) : MT;
        ++nt;
      }
      base += tot;
    }
    *tileCount = nt;
  }
  __syncthreads();
  if (t < NE) {
    int run = bases[t];
    for (int b = 0; b < NB; ++b) {
      startEB[t * NB + b] = run;
      run += blockCounts[t * NB + b];
    }
  }
}

__global__ void place_kernel(const int* __restrict__ slot_e, const float* __restrict__ slot_w,
                             const int* __restrict__ startEB,
                             int* __restrict__ perm_token, float* __restrict__ perm_w) {
  __shared__ int se[256];
  __shared__ float sw[256];
  int b = blockIdx.x;
  for (int i = threadIdx.x; i < 256; i += 64) {
    se[i] = slot_e[b * 256 + i];
    sw[i] = slot_w[b * 256 + i];
  }
  __syncthreads();
  int e = threadIdx.x;
  if (e < NE) {
    int pos = startEB[e * NB + b];
    for (int i = 0; i < 256; ++i) {
      if (se[i] == e) {
        perm_token[pos] = (b * 256 + i) >> 3;
        perm_w[pos] = sw[i];
        ++pos;
      }
    }
  }
}

// ---------------- grouped gate_up GEMM + silu*mul ----------------
// tile: 128 rows x 64 h-cols; computes g (wgu rows n0..n0+63) and u (768+n0..)
__global__ __launch_bounds__(256, 2) void gu_kernel(
    const u16* __restrict__ xb, const float* __restrict__ wgu,
    const int* __restrict__ perm_token,
    const int* __restrict__ tile_e, const int* __restrict__ tile_row0,
    const int* __restrict__ tile_cnt, const int* __restrict__ tileCount,
    u16* __restrict__ h_perm) {
  int tile = blockIdx.x;
  if (tile >= *tileCount) return;
  int e = tile_e[tile], row0 = tile_row0[tile], cnt = tile_cnt[tile];
  int n0 = blockIdx.y * 64;
  __shared__ u16 As[MT * 64];
  __shared__ u16 Bg[64 * 64];
  __shared__ u16 Bu[64 * 64];
  __shared__ int toks[MT];
  if (threadIdx.x < MT) {
    int idx = row0 + (int)threadIdx.x;
    if (idx > NSLOT - 1) idx = NSLOT - 1;
    toks[threadIdx.x] = perm_token[idx];
  }
  int wave = threadIdx.x >> 6, lane = threadIdx.x & 63;
  int wr = wave >> 1, wc = wave & 1;
  int lr = lane & 15, lk = lane >> 4;
  f32x4 zero = {0.f, 0.f, 0.f, 0.f};
  f32x4 accg[4][2], accu[4][2];
#pragma unroll
  for (int m = 0; m < 4; ++m)
#pragma unroll
    for (int n = 0; n < 2; ++n) { accg[m][n] = zero; accu[m][n] = zero; }

  int achunk = threadIdx.x & 7, arow = threadIdx.x >> 3;
  int bfc = threadIdx.x & 15, brow = threadIdx.x >> 4;
  const float* wbaseg = wgu + (size_t)e * (2 * DFF) * HID + (size_t)n0 * HID;
  const float* wbaseu = wbaseg + (size_t)DFF * HID;

  for (int kt = 0; kt < HID; kt += 64) {
    __syncthreads();
    // stage A (gathered token rows, bf16 copy), swizzled
#pragma unroll
    for (int g = 0; g < 4; ++g) {
      int r = g * 32 + arow;
      const u16* src = xb + (size_t)toks[r] * HID + kt + achunk * 8;
      uint4 v = *reinterpret_cast<const uint4*>(src);
      int byte = (r * 128 + achunk * 16) ^ ((r & 7) << 4);
      *reinterpret_cast<uint4*>(reinterpret_cast<char*>(As) + byte) = v;
    }
    // stage Bg/Bu (fp32 -> bf16), swizzled
#pragma unroll
    for (int g = 0; g < 4; ++g) {
      int r = g * 16 + brow;
      float4 vg = *reinterpret_cast<const float4*>(wbaseg + (size_t)r * HID + kt + bfc * 4);
      float4 vu = *reinterpret_cast<const float4*>(wbaseu + (size_t)r * HID + kt + bfc * 4);
      int byte = (r * 128 + bfc * 8) ^ ((r & 7) << 4);
      uint2 pg = make_uint2((u32)f2bf(vg.x) | ((u32)f2bf(vg.y) << 16),
                            (u32)f2bf(vg.z) | ((u32)f2bf(vg.w) << 16));
      uint2 pu = make_uint2((u32)f2bf(vu.x) | ((u32)f2bf(vu.y) << 16),
                            (u32)f2bf(vu.z) | ((u32)f2bf(vu.w) << 16));
      *reinterpret_cast<uint2*>(reinterpret_cast<char*>(Bg) + byte) = pg;
      *reinterpret_cast<uint2*>(reinterpret_cast<char*>(Bu) + byte) = pu;
    }
    __syncthreads();
#pragma unroll
    for (int kf = 0; kf < 2; ++kf) {
      int kb = kf * 64 + lk * 16;
      bf16x8 a[4], bg2[2], bu2[2];
#pragma unroll
      for (int m = 0; m < 4; ++m) {
        int row = wr * 64 + m * 16 + lr;
        a[m] = *reinterpret_cast<bf16x8*>(reinterpret_cast<char*>(As) + ((row * 128 + kb) ^ ((row & 7) << 4)));
      }
#pragma unroll
      for (int n = 0; n < 2; ++n) {
        int row = wc * 32 + n * 16 + lr;
        int byte = (row * 128 + kb) ^ ((row & 7) << 4);
        bg2[n] = *reinterpret_cast<bf16x8*>(reinterpret_cast<char*>(Bg) + byte);
        bu2[n] = *reinterpret_cast<bf16x8*>(reinterpret_cast<char*>(Bu) + byte);
      }
#pragma unroll
      for (int m = 0; m < 4; ++m)
#pragma unroll
        for (int n = 0; n < 2; ++n) {
          accg[m][n] = __builtin_amdgcn_mfma_f32_16x16x32_bf16(a[m], bg2[n], accg[m][n], 0, 0, 0);
          accu[m][n] = __builtin_amdgcn_mfma_f32_16x16x32_bf16(a[m], bu2[n], accu[m][n], 0, 0, 0);
        }
    }
  }
  // epilogue: h = silu(g)*u  (C/D: col=lane&15, row=(lane>>4)*4+reg)
#pragma unroll
  for (int m = 0; m < 4; ++m)
#pragma unroll
    for (int n = 0; n < 2; ++n)
#pragma unroll
      for (int i = 0; i < 4; ++i) {
        int row = wr * 64 + m * 16 + lk * 4 + i;
        if (row < cnt) {
          int col = n0 + wc * 32 + n * 16 + lr;
          float g = accg[m][n][i], u = accu[m][n][i];
          float h = g / (1.f + __expf(-g)) * u;
          h_perm[(size_t)(row0 + row) * DFF + col] = f2bf(h);
        }
      }
}

// ---------------- grouped down GEMM + weighted scatter-add ----------------
__global__ __launch_bounds__(256, 2) void down_kernel(
    const u16* __restrict__ h_perm, const float* __restrict__ wd,
    const int* __restrict__ perm_token, const float* __restrict__ perm_w,
    const int* __restrict__ tile_e, const int* __restrict__ tile_row0,
    const int* __restrict__ tile_cnt, const int* __restrict__ tileCount,
    float* __restrict__ y) {
  int tile = blockIdx.x;
  if (tile >= *tileCount) return;
  int e = tile_e[tile], row0 = tile_row0[tile], cnt = tile_cnt[tile];
  int n0 = blockIdx.y * 128;
  __shared__ u16 As[MT * 64];
  __shared__ u16 Bs[MT * 64];
  __shared__ int toks[MT];
  __shared__ float wts[MT];
  if (threadIdx.x < MT) {
    int idx = row0 + (int)threadIdx.x;
    if (idx > NSLOT - 1) idx = NSLOT - 1;
    toks[threadIdx.x] = perm_token[idx];
    wts[threadIdx.x] = perm_w[idx];
  }
  int wave = threadIdx.x >> 6, lane = threadIdx.x & 63;
  int wr = wave >> 1, wc = wave & 1;
  int lr = lane & 15, lk = lane >> 4;
  f32x4 zero = {0.f, 0.f, 0.f, 0.f};
  f32x4 acc[4][4];
#pragma unroll
  for (int m = 0; m < 4; ++m)
#pragma unroll
    for (int n = 0; n < 4; ++n) acc[m][n] = zero;

  int achunk = threadIdx.x & 7, arow = threadIdx.x >> 3;
  int bfc = threadIdx.x & 15, brow = threadIdx.x >> 4;
  const float* wbase = wd + (size_t)e * HID * DFF + (size_t)n0 * DFF;

  for (int kt = 0; kt < DFF; kt += 64) {
    __syncthreads();
#pragma unroll
    for (int g = 0; g < 4; ++g) {
      int r = g * 32 + arow;
      int idx = row0 + r;
      if (idx > NSLOT - 1) idx = NSLOT - 1;
      const u16* src = h_perm + (size_t)idx * DFF + kt + achunk * 8;
      uint4 v = *reinterpret_cast<const uint4*>(src);
      int byte = (r * 128 + achunk * 16) ^ ((r & 7) << 4);
      *reinterpret_cast<uint4*>(reinterpret_cast<char*>(As) + byte) = v;
    }
#pragma unroll
    for (int g = 0; g < 8; ++g) {
      int r = g * 16 + brow;
      float4 v = *reinterpret_cast<const float4*>(wbase + (size_t)r * DFF + kt + bfc * 4);
      int byte = (r * 128 + bfc * 8) ^ ((r & 7) << 4);
      uint2 p = make_uint2((u32)f2bf(v.x) | ((u32)f2bf(v.y) << 16),
                           (u32)f2bf(v.z) | ((u32)f2bf(v.w) << 16));
      *reinterpret_cast<uint2*>(reinterpret_cast<char*>(Bs) + byte) = p;
    }
    __syncthreads();
#pragma unroll
    for (int kf = 0; kf < 2; ++kf) {
      int kb = kf * 64 + lk * 16;
      bf16x8 a[4], b[4];
#pragma unroll
      for (int m = 0; m < 4; ++m) {
        int row = wr * 64 + m * 16 + lr;
        a[m] = *reinterpret_cast<bf16x8*>(reinterpret_cast<char*>(As) + ((row * 128 + kb) ^ ((row & 7) << 4)));
      }
#pragma unroll
      for (int n = 0; n < 4; ++n) {
        int row = wc * 64 + n * 16 + lr;
        b[n] = *reinterpret_cast<bf16x8*>(reinterpret_cast<char*>(Bs) + ((row * 128 + kb) ^ ((row & 7) << 4)));
      }
#pragma unroll
      for (int m = 0; m < 4; ++m)
#pragma unroll
        for (int n = 0; n < 4; ++n)
          acc[m][n] = __builtin_amdgcn_mfma_f32_16x16x32_bf16(a[m], b[n], acc[m][n], 0, 0, 0);
    }
  }
#pragma unroll
  for (int m = 0; m < 4; ++m)
#pragma unroll
    for (int n = 0; n < 4; ++n)
#pragma unroll
      for (int i = 0; i < 4; ++i) {
        int row = wr * 64 + m * 16 + lk * 4 + i;
        if (row < cnt) {
          int col = n0 + wc * 64 + n * 16 + lr;
          float v = acc[m][n][i] * wts[row];
          atomicAdd(&y[(size_t)toks[row] * HID + col], v);
        }
      }
}

extern "C" void kernel_launch(void* const* d_in, const int* in_sizes, int n_in,
                              void* d_out, int out_size, void* d_ws, size_t ws_size,
                              hipStream_t stream) {
  const float* x = (const float*)d_in[0];
  const float* gw = (const float*)d_in[1];
  const float* wgu = (const float*)d_in[2];
  const float* wd = (const float*)d_in[3];
  const float* sim = (const float*)d_in[4];
  float* y = (float*)d_out;

  char* ws = (char*)d_ws;
  size_t off = 0;
  auto alloc = [&](size_t bytes) {
    char* p = ws + off;
    off += (bytes + 255) & ~(size_t)255;
    return p;
  };
  u16* xb = (u16*)alloc((size_t)NTOK * HID * 2);
  u16* h_perm = (u16*)alloc((size_t)NSLOT * DFF * 2);
  int* slot_e = (int*)alloc(NSLOT * 4);
  float* slot_w = (float*)alloc(NSLOT * 4);
  int* perm_token = (int*)alloc(NSLOT * 4);
  float* perm_w = (float*)alloc(NSLOT * 4);
  int* blockCounts = (int*)alloc(NE * NB * 4);
  int* startEB = (int*)alloc(NE * NB * 4);
  int* tile_e = (int*)alloc(MAX_TILES * 4);
  int* tile_row0 = (int*)alloc(MAX_TILES * 4);
  int* tile_cnt = (int*)alloc(MAX_TILES * 4);
  int* tileCount = (int*)alloc(4);
  if (off > ws_size) return;  // workspace too small: bail (will fail loudly, not crash)

  hipMemsetAsync(d_out, 0, (size_t)NTOK * HID * sizeof(float), stream);
  convert_x_kernel<<<2048, 256, 0, stream>>>(x, xb, NTOK * HID / 4);
  router_kernel<<<NTOK, 256, 0, stream>>>(x, gw, sim, slot_e, slot_w);
  hist_kernel<<<NB, 256, 0, stream>>>(slot_e, blockCounts);
  scan_kernel<<<1, 64, 0, stream>>>(blockCounts, startEB, tile_e, tile_row0, tile_cnt, tileCount);
  place_kernel<<<NB, 64, 0, stream>>>(slot_e, slot_w, startEB, perm_token, perm_w);
  gu_kernel<<<dim3(MAX_TILES, DFF / 64), 256, 0, stream>>>(xb, wgu, perm_token, tile_e, tile_row0,
                                                           tile_cnt, tileCount, h_perm);
  down_kernel<<<dim3(MAX_TILES, HID / 128), 256, 0, stream>>>(h_perm, wd, perm_token, perm_w,
                                                              tile_e, tile_row0, tile_cnt,
                                                              tileCount, y);
}

// Round 2
// 1588.267 us; speedup vs baseline: 1.3009x; 1.3009x over previous
//
#include <hip/hip_runtime.h>
#include <stdint.h>
#include <string.h>

#define NTOK 8192
#define HID 2048
#define NE 32
#define DFF 768
#define NSLOT 65536
#define NB 256
#define MT 128
#define MAX_TILES 544   // 65536/128 + 32

typedef unsigned short u16;
typedef unsigned int u32;

using f32x4 = __attribute__((ext_vector_type(4))) float;
using bf16x8 = __attribute__((ext_vector_type(8))) short;

static __device__ __forceinline__ u16 f2bf(float f) {
  u32 x = __float_as_uint(f);
  x += 0x7fffu + ((x >> 16) & 1u);
  return (u16)(x >> 16);
}

typedef const __attribute__((address_space(1))) unsigned int* gp_t;
typedef __attribute__((address_space(3))) unsigned int* lp_t;
static __device__ __forceinline__ void gload16(const void* g, void* l) {
  __builtin_amdgcn_global_load_lds((gp_t)g, (lp_t)l, 16, 0, 0);
}

// ---------------- fp32 -> bf16 convert (x and weights) ----------------
__global__ void convertf2b_kernel(const float* __restrict__ src, u16* __restrict__ dst, int n4) {
  int i = blockIdx.x * blockDim.x + threadIdx.x;
  int stride = gridDim.x * blockDim.x;
  for (; i < n4; i += stride) {
    float4 v = reinterpret_cast<const float4*>(src)[i];
    u32 lo = (u32)f2bf(v.x) | ((u32)f2bf(v.y) << 16);
    u32 hi = (u32)f2bf(v.z) | ((u32)f2bf(v.w) << 16);
    reinterpret_cast<uint2*>(dst)[i] = make_uint2(lo, hi);
  }
}

// ---------------- router: logits + softmax + top8 + reroute ----------------
__global__ void router_kernel(const float* __restrict__ x, const float* __restrict__ gw,
                              const float* __restrict__ sim,
                              int* __restrict__ slot_e, float* __restrict__ slot_w) {
  int t = blockIdx.x;
  __shared__ float xs[HID];
  __shared__ float logits[NE];
  const float* xr = x + (size_t)t * HID;
  for (int i = threadIdx.x; i < HID / 4; i += 256)
    reinterpret_cast<float4*>(xs)[i] = reinterpret_cast<const float4*>(xr)[i];
  __syncthreads();
  int e = threadIdx.x >> 3, part = threadIdx.x & 7;
  const float4* wv = reinterpret_cast<const float4*>(gw + (size_t)e * HID + part * 256);
  const float4* xv = reinterpret_cast<const float4*>(xs + part * 256);
  float s = 0.f;
#pragma unroll
  for (int j = 0; j < 64; ++j) {
    float4 a = xv[j], b = wv[j];
    s += a.x * b.x + a.y * b.y + a.z * b.z + a.w * b.w;
  }
  s += __shfl_xor(s, 1); s += __shfl_xor(s, 2); s += __shfl_xor(s, 4);
  if (part == 0) logits[e] = s;
  __syncthreads();
  if (threadIdx.x == 0) {
    float l[NE];
#pragma unroll
    for (int i = 0; i < NE; ++i) l[i] = logits[i];
    unsigned mask = 0;
    int idx[8]; float lv[8];
#pragma unroll
    for (int k = 0; k < 8; ++k) {
      float best = -3.4e38f; int bi = 0;
#pragma unroll
      for (int i = 0; i < NE; ++i) {
        bool ok = (((mask >> i) & 1u) == 0u) && (l[i] > best);
        best = ok ? l[i] : best;
        bi = ok ? i : bi;
      }
      idx[k] = bi; lv[k] = best; mask |= (1u << bi);
    }
    float w[8]; float ssum = 0.f;
#pragma unroll
    for (int k = 0; k < 8; ++k) { w[k] = __expf(lv[k] - lv[0]); ssum += w[k]; }
    float inv = 1.f / ssum;
    int base = t * 8;
#pragma unroll
    for (int i = 0; i < 4; ++i) { slot_e[base + i] = idx[i]; slot_w[base + i] = w[i] * inv; }
#pragma unroll
    for (int j = 0; j < 4; ++j) {
      int sj = idx[4 + j];
      float best = -2.f; int bsel = idx[0];
#pragma unroll
      for (int i = 0; i < 4; ++i) {
        int pe = idx[i];
        float sv = sim[sj * NE + pe];
        bool ok = sv > best;
        best = ok ? sv : best;
        bsel = ok ? pe : bsel;
      }
      int ns = (best < 0.5f) ? sj : bsel;
      slot_e[base + 4 + j] = ns; slot_w[base + 4 + j] = w[4 + j] * inv;
    }
  }
}

// ---------------- counting sort: hist / scan / place ----------------
__global__ void hist_kernel(const int* __restrict__ slot_e, int* __restrict__ blockCounts) {
  __shared__ int cnt[NE];
  if (threadIdx.x < NE) cnt[threadIdx.x] = 0;
  __syncthreads();
  int i = blockIdx.x * 256 + threadIdx.x;
  atomicAdd(&cnt[slot_e[i]], 1);
  __syncthreads();
  if (threadIdx.x < NE) blockCounts[threadIdx.x * NB + blockIdx.x] = cnt[threadIdx.x];
}

__global__ void scan_kernel(const int* __restrict__ blockCounts, int* __restrict__ startEB,
                            int* __restrict__ tile_e, int* __restrict__ tile_row0,
                            int* __restrict__ tile_cnt, int* __restrict__ tileCount) {
  __shared__ int totals[NE];
  __shared__ int bases[NE];
  int t = threadIdx.x;
  if (t < NE) {
    int run = 0;
    for (int b = 0; b < NB; ++b) run += blockCounts[t * NB + b];
    totals[t] = run;
  }
  __syncthreads();
  if (t == 0) {
    int base = 0, nt = 0;
    for (int e = 0; e < NE; ++e) {
      bases[e] = base;
      int tot = totals[e];
      for (int i = 0; i < tot; i += MT) {
        tile_e[nt] = e;
        tile_row0[nt] = base + i;
        tile_cnt[nt] = (tot - i < MT) ? (tot - i) : MT;
        ++nt;
      }
      base += tot;
    }
    *tileCount = nt;
  }
  __syncthreads();
  if (t < NE) {
    int run = bases[t];
    for (int b = 0; b < NB; ++b) {
      startEB[t * NB + b] = run;
      run += blockCounts[t * NB + b];
    }
  }
}

__global__ void place_kernel(const int* __restrict__ slot_e, const float* __restrict__ slot_w,
                             const int* __restrict__ startEB,
                             int* __restrict__ perm_token, float* __restrict__ perm_w,
                             int* __restrict__ inv) {
  __shared__ int se[256];
  __shared__ float sw[256];
  int b = blockIdx.x;
  for (int i = threadIdx.x; i < 256; i += 64) {
    se[i] = slot_e[b * 256 + i];
    sw[i] = slot_w[b * 256 + i];
  }
  __syncthreads();
  int e = threadIdx.x;
  if (e < NE) {
    int pos = startEB[e * NB + b];
    for (int i = 0; i < 256; ++i) {
      if (se[i] == e) {
        perm_token[pos] = (b * 256 + i) >> 3;
        perm_w[pos] = sw[i];
        inv[b * 256 + i] = pos;
        ++pos;
      }
    }
  }
}

// ---------------- fast gate_up GEMM (bf16 weights, global_load_lds) ----------------
__global__ __launch_bounds__(256) void gu_fast(
    const u16* __restrict__ xb, const u16* __restrict__ wgub,
    const int* __restrict__ perm_token,
    const int* __restrict__ tile_e, const int* __restrict__ tile_row0,
    const int* __restrict__ tile_cnt, const int* __restrict__ tileCount,
    u16* __restrict__ h_perm) {
  int tile = blockIdx.x;
  if (tile >= *tileCount) return;
  int e = tile_e[tile], row0 = tile_row0[tile], cnt = tile_cnt[tile];
  int n0 = blockIdx.y * 64;
  __shared__ __align__(16) u16 As[MT * 64];   // 128 rows x 64, XOR-swizzled via source
  __shared__ __align__(16) u16 Bs[MT * 64];   // rows 0-63 = gate, 64-127 = up
  __shared__ int toks[MT];
  if (threadIdx.x < MT) {
    int idx = row0 + (int)threadIdx.x;
    if (idx > NSLOT - 1) idx = NSLOT - 1;
    toks[threadIdx.x] = perm_token[idx];
  }
  int wave = threadIdx.x >> 6, lane = threadIdx.x & 63;
  int wr = wave >> 1, wc = wave & 1;
  int lr = lane & 15, lk = lane >> 4;
  f32x4 zero = {0.f, 0.f, 0.f, 0.f};
  f32x4 accg[4][2], accu[4][2];
#pragma unroll
  for (int m = 0; m < 4; ++m)
#pragma unroll
    for (int n = 0; n < 2; ++n) { accg[m][n] = zero; accu[m][n] = zero; }

  const u16* wgb = wgub + (size_t)e * (2 * DFF) * HID;
  int r_ = (wave * 64 + lane) >> 3;          // base row for issue i=0
  int c_ = lane & 7;

  for (int kt = 0; kt < HID; kt += 64) {
    __syncthreads();
    // A: 16KB, linear LDS dest, source chunk pre-swizzled (j = c ^ (r&7))
#pragma unroll
    for (int i = 0; i < 4; ++i) {
      int r = r_ + i * 32;                    // rows advance 32 per issue (4 waves x 8 rows)
      int j = c_ ^ (r & 7);
      gload16(xb + (size_t)toks[r] * HID + kt + j * 8, (char*)As + (i * 4 + wave) * 1024);
    }
    // B: 16KB (gate rows then up rows)
#pragma unroll
    for (int i = 0; i < 4; ++i) {
      int r = r_ + i * 32;
      int j = c_ ^ (r & 7);
      int wrow = (r < 64) ? (n0 + r) : (DFF + n0 + (r - 64));
      gload16(wgb + (size_t)wrow * HID + kt + j * 8, (char*)Bs + (i * 4 + wave) * 1024);
    }
    __syncthreads();
#pragma unroll
    for (int kf = 0; kf < 2; ++kf) {
      int kb = kf * 64 + lk * 16;
      bf16x8 a[4], bg2[2], bu2[2];
#pragma unroll
      for (int m = 0; m < 4; ++m) {
        int row = wr * 64 + m * 16 + lr;
        a[m] = *reinterpret_cast<bf16x8*>(reinterpret_cast<char*>(As) + ((row * 128 + kb) ^ ((row & 7) << 4)));
      }
#pragma unroll
      for (int n = 0; n < 2; ++n) {
        int rg = wc * 32 + n * 16 + lr;
        int ru = 64 + rg;
        bg2[n] = *reinterpret_cast<bf16x8*>(reinterpret_cast<char*>(Bs) + ((rg * 128 + kb) ^ ((rg & 7) << 4)));
        bu2[n] = *reinterpret_cast<bf16x8*>(reinterpret_cast<char*>(Bs) + ((ru * 128 + kb) ^ ((ru & 7) << 4)));
      }
#pragma unroll
      for (int m = 0; m < 4; ++m)
#pragma unroll
        for (int n = 0; n < 2; ++n) {
          accg[m][n] = __builtin_amdgcn_mfma_f32_16x16x32_bf16(a[m], bg2[n], accg[m][n], 0, 0, 0);
          accu[m][n] = __builtin_amdgcn_mfma_f32_16x16x32_bf16(a[m], bu2[n], accu[m][n], 0, 0, 0);
        }
    }
  }
#pragma unroll
  for (int m = 0; m < 4; ++m)
#pragma unroll
    for (int n = 0; n < 2; ++n)
#pragma unroll
      for (int i = 0; i < 4; ++i) {
        int row = wr * 64 + m * 16 + lk * 4 + i;
        if (row < cnt) {
          int col = n0 + wc * 32 + n * 16 + lr;
          float g = accg[m][n][i], u = accu[m][n][i];
          float h = g / (1.f + __expf(-g)) * u;
          h_perm[(size_t)(row0 + row) * DFF + col] = f2bf(h);
        }
      }
}

// ---------------- fast down GEMM -> yp (fp16, perm order) ----------------
__global__ __launch_bounds__(256) void down_fast(
    const u16* __restrict__ h_perm, const u16* __restrict__ wdb,
    const float* __restrict__ perm_w,
    const int* __restrict__ tile_e, const int* __restrict__ tile_row0,
    const int* __restrict__ tile_cnt, const int* __restrict__ tileCount,
    _Float16* __restrict__ yp) {
  int tile = blockIdx.x;
  if (tile >= *tileCount) return;
  int e = tile_e[tile], row0 = tile_row0[tile], cnt = tile_cnt[tile];
  int n0 = blockIdx.y * 128;
  __shared__ __align__(16) u16 As[MT * 64];
  __shared__ __align__(16) u16 Bs[MT * 64];
  __shared__ float wts[MT];
  if (threadIdx.x < MT) {
    int idx = row0 + (int)threadIdx.x;
    if (idx > NSLOT - 1) idx = NSLOT - 1;
    wts[threadIdx.x] = perm_w[idx];
  }
  int wave = threadIdx.x >> 6, lane = threadIdx.x & 63;
  int wr = wave >> 1, wc = wave & 1;
  int lr = lane & 15, lk = lane >> 4;
  f32x4 zero = {0.f, 0.f, 0.f, 0.f};
  f32x4 acc[4][4];
#pragma unroll
  for (int m = 0; m < 4; ++m)
#pragma unroll
    for (int n = 0; n < 4; ++n) acc[m][n] = zero;

  const u16* wb = wdb + (size_t)e * HID * DFF;
  int r_ = (wave * 64 + lane) >> 3;
  int c_ = lane & 7;

  for (int kt = 0; kt < DFF; kt += 64) {
    __syncthreads();
#pragma unroll
    for (int i = 0; i < 4; ++i) {
      int r = r_ + i * 32;
      int j = c_ ^ (r & 7);
      int idx = row0 + r;
      if (idx > NSLOT - 1) idx = NSLOT - 1;
      gload16(h_perm + (size_t)idx * DFF + kt + j * 8, (char*)As + (i * 4 + wave) * 1024);
    }
#pragma unroll
    for (int i = 0; i < 4; ++i) {
      int r = r_ + i * 32;
      int j = c_ ^ (r & 7);
      gload16(wb + (size_t)(n0 + r) * DFF + kt + j * 8, (char*)Bs + (i * 4 + wave) * 1024);
    }
    __syncthreads();
#pragma unroll
    for (int kf = 0; kf < 2; ++kf) {
      int kb = kf * 64 + lk * 16;
      bf16x8 a[4], b[4];
#pragma unroll
      for (int m = 0; m < 4; ++m) {
        int row = wr * 64 + m * 16 + lr;
        a[m] = *reinterpret_cast<bf16x8*>(reinterpret_cast<char*>(As) + ((row * 128 + kb) ^ ((row & 7) << 4)));
      }
#pragma unroll
      for (int n = 0; n < 4; ++n) {
        int row = wc * 64 + n * 16 + lr;
        b[n] = *reinterpret_cast<bf16x8*>(reinterpret_cast<char*>(Bs) + ((row * 128 + kb) ^ ((row & 7) << 4)));
      }
#pragma unroll
      for (int m = 0; m < 4; ++m)
#pragma unroll
        for (int n = 0; n < 4; ++n)
          acc[m][n] = __builtin_amdgcn_mfma_f32_16x16x32_bf16(a[m], b[n], acc[m][n], 0, 0, 0);
    }
  }
#pragma unroll
  for (int m = 0; m < 4; ++m)
#pragma unroll
    for (int n = 0; n < 4; ++n)
#pragma unroll
      for (int i = 0; i < 4; ++i) {
        int row = wr * 64 + m * 16 + lk * 4 + i;
        if (row < cnt) {
          int col = n0 + wc * 64 + n * 16 + lr;
          yp[(size_t)(row0 + row) * HID + col] = (_Float16)(acc[m][n][i] * wts[row]);
        }
      }
}

// ---------------- per-token gather-reduce of 8 slots ----------------
__global__ void reduce_kernel(const _Float16* __restrict__ yp, const int* __restrict__ inv,
                              float* __restrict__ y) {
  int t = blockIdx.x;
  __shared__ int pos[8];
  if (threadIdx.x < 8) pos[threadIdx.x] = inv[t * 8 + threadIdx.x];
  __syncthreads();
  int c = threadIdx.x * 8;
  float s[8] = {0.f, 0.f, 0.f, 0.f, 0.f, 0.f, 0.f, 0.f};
#pragma unroll
  for (int j = 0; j < 8; ++j) {
    uint4 v = *reinterpret_cast<const uint4*>(yp + (size_t)pos[j] * HID + c);
    const u16* p = reinterpret_cast<const u16*>(&v);
#pragma unroll
    for (int k = 0; k < 8; ++k) {
      _Float16 h;
      u16 us = p[k];
      __builtin_memcpy(&h, &us, 2);
      s[k] += (float)h;
    }
  }
  float* yo = y + (size_t)t * HID + c;
  float4 o0 = {s[0], s[1], s[2], s[3]};
  float4 o1 = {s[4], s[5], s[6], s[7]};
  *reinterpret_cast<float4*>(yo) = o0;
  *reinterpret_cast<float4*>(yo + 4) = o1;
}

// ================= legacy (round-1) kernels: ws-size fallback =================
__global__ __launch_bounds__(256, 2) void gu_legacy(
    const u16* __restrict__ xb, const float* __restrict__ wgu,
    const int* __restrict__ perm_token,
    const int* __restrict__ tile_e, const int* __restrict__ tile_row0,
    const int* __restrict__ tile_cnt, const int* __restrict__ tileCount,
    u16* __restrict__ h_perm) {
  int tile = blockIdx.x;
  if (tile >= *tileCount) return;
  int e = tile_e[tile], row0 = tile_row0[tile], cnt = tile_cnt[tile];
  int n0 = blockIdx.y * 64;
  __shared__ __align__(16) u16 As[MT * 64];
  __shared__ __align__(16) u16 Bg[64 * 64];
  __shared__ __align__(16) u16 Bu[64 * 64];
  __shared__ int toks[MT];
  if (threadIdx.x < MT) {
    int idx = row0 + (int)threadIdx.x;
    if (idx > NSLOT - 1) idx = NSLOT - 1;
    toks[threadIdx.x] = perm_token[idx];
  }
  int wave = threadIdx.x >> 6, lane = threadIdx.x & 63;
  int wr = wave >> 1, wc = wave & 1;
  int lr = lane & 15, lk = lane >> 4;
  f32x4 zero = {0.f, 0.f, 0.f, 0.f};
  f32x4 accg[4][2], accu[4][2];
#pragma unroll
  for (int m = 0; m < 4; ++m)
#pragma unroll
    for (int n = 0; n < 2; ++n) { accg[m][n] = zero; accu[m][n] = zero; }
  int achunk = threadIdx.x & 7, arow = threadIdx.x >> 3;
  int bfc = threadIdx.x & 15, brow = threadIdx.x >> 4;
  const float* wbaseg = wgu + (size_t)e * (2 * DFF) * HID + (size_t)n0 * HID;
  const float* wbaseu = wbaseg + (size_t)DFF * HID;
  for (int kt = 0; kt < HID; kt += 64) {
    __syncthreads();
#pragma unroll
    for (int g = 0; g < 4; ++g) {
      int r = g * 32 + arow;
      const u16* src = xb + (size_t)toks[r] * HID + kt + achunk * 8;
      uint4 v = *reinterpret_cast<const uint4*>(src);
      int byte = (r * 128 + achunk * 16) ^ ((r & 7) << 4);
      *reinterpret_cast<uint4*>(reinterpret_cast<char*>(As) + byte) = v;
    }
#pragma unroll
    for (int g = 0; g < 4; ++g) {
      int r = g * 16 + brow;
      float4 vg = *reinterpret_cast<const float4*>(wbaseg + (size_t)r * HID + kt + bfc * 4);
      float4 vu = *reinterpret_cast<const float4*>(wbaseu + (size_t)r * HID + kt + bfc * 4);
      int byte = (r * 128 + bfc * 8) ^ ((r & 7) << 4);
      uint2 pg = make_uint2((u32)f2bf(vg.x) | ((u32)f2bf(vg.y) << 16),
                            (u32)f2bf(vg.z) | ((u32)f2bf(vg.w) << 16));
      uint2 pu = make_uint2((u32)f2bf(vu.x) | ((u32)f2bf(vu.y) << 16),
                            (u32)f2bf(vu.z) | ((u32)f2bf(vu.w) << 16));
      *reinterpret_cast<uint2*>(reinterpret_cast<char*>(Bg) + byte) = pg;
      *reinterpret_cast<uint2*>(reinterpret_cast<char*>(Bu) + byte) = pu;
    }
    __syncthreads();
#pragma unroll
    for (int kf = 0; kf < 2; ++kf) {
      int kb = kf * 64 + lk * 16;
      bf16x8 a[4], bg2[2], bu2[2];
#pragma unroll
      for (int m = 0; m < 4; ++m) {
        int row = wr * 64 + m * 16 + lr;
        a[m] = *reinterpret_cast<bf16x8*>(reinterpret_cast<char*>(As) + ((row * 128 + kb) ^ ((row & 7) << 4)));
      }
#pragma unroll
      for (int n = 0; n < 2; ++n) {
        int row = wc * 32 + n * 16 + lr;
        int byte = (row * 128 + kb) ^ ((row & 7) << 4);
        bg2[n] = *reinterpret_cast<bf16x8*>(reinterpret_cast<char*>(Bg) + byte);
        bu2[n] = *reinterpret_cast<bf16x8*>(reinterpret_cast<char*>(Bu) + byte);
      }
#pragma unroll
      for (int m = 0; m < 4; ++m)
#pragma unroll
        for (int n = 0; n < 2; ++n) {
          accg[m][n] = __builtin_amdgcn_mfma_f32_16x16x32_bf16(a[m], bg2[n], accg[m][n], 0, 0, 0);
          accu[m][n] = __builtin_amdgcn_mfma_f32_16x16x32_bf16(a[m], bu2[n], accu[m][n], 0, 0, 0);
        }
    }
  }
#pragma unroll
  for (int m = 0; m < 4; ++m)
#pragma unroll
    for (int n = 0; n < 2; ++n)
#pragma unroll
      for (int i = 0; i < 4; ++i) {
        int row = wr * 64 + m * 16 + lk * 4 + i;
        if (row < cnt) {
          int col = n0 + wc * 32 + n * 16 + lr;
          float g = accg[m][n][i], u = accu[m][n][i];
          float h = g / (1.f + __expf(-g)) * u;
          h_perm[(size_t)(row0 + row) * DFF + col] = f2bf(h);
        }
      }
}

__global__ __launch_bounds__(256, 2) void down_legacy(
    const u16* __restrict__ h_perm, const float* __restrict__ wd,
    const int* __restrict__ perm_token, const float* __restrict__ perm_w,
    const int* __restrict__ tile_e, const int* __restrict__ tile_row0,
    const int* __restrict__ tile_cnt, const int* __restrict__ tileCount,
    float* __restrict__ y) {
  int tile = blockIdx.x;
  if (tile >= *tileCount) return;
  int e = tile_e[tile], row0 = tile_row0[tile], cnt = tile_cnt[tile];
  int n0 = blockIdx.y * 128;
  __shared__ __align__(16) u16 As[MT * 64];
  __shared__ __align__(16) u16 Bs[MT * 64];
  __shared__ int toks[MT];
  __shared__ float wts[MT];
  if (threadIdx.x < MT) {
    int idx = row0 + (int)threadIdx.x;
    if (idx > NSLOT - 1) idx = NSLOT - 1;
    toks[threadIdx.x] = perm_token[idx];
    wts[threadIdx.x] = perm_w[idx];
  }
  int wave = threadIdx.x >> 6, lane = threadIdx.x & 63;
  int wr = wave >> 1, wc = wave & 1;
  int lr = lane & 15, lk = lane >> 4;
  f32x4 zero = {0.f, 0.f, 0.f, 0.f};
  f32x4 acc[4][4];
#pragma unroll
  for (int m = 0; m < 4; ++m)
#pragma unroll
    for (int n = 0; n < 4; ++n) acc[m][n] = zero;
  int achunk = threadIdx.x & 7, arow = threadIdx.x >> 3;
  int bfc = threadIdx.x & 15, brow = threadIdx.x >> 4;
  const float* wbase = wd + (size_t)e * HID * DFF + (size_t)n0 * DFF;
  for (int kt = 0; kt < DFF; kt += 64) {
    __syncthreads();
#pragma unroll
    for (int g = 0; g < 4; ++g) {
      int r = g * 32 + arow;
      int idx = row0 + r;
      if (idx > NSLOT - 1) idx = NSLOT - 1;
      const u16* src = h_perm + (size_t)idx * DFF + kt + achunk * 8;
      uint4 v = *reinterpret_cast<const uint4*>(src);
      int byte = (r * 128 + achunk * 16) ^ ((r & 7) << 4);
      *reinterpret_cast<uint4*>(reinterpret_cast<char*>(As) + byte) = v;
    }
#pragma unroll
    for (int g = 0; g < 8; ++g) {
      int r = g * 16 + brow;
      float4 v = *reinterpret_cast<const float4*>(wbase + (size_t)r * DFF + kt + bfc * 4);
      int byte = (r * 128 + bfc * 8) ^ ((r & 7) << 4);
      uint2 p = make_uint2((u32)f2bf(v.x) | ((u32)f2bf(v.y) << 16),
                           (u32)f2bf(v.z) | ((u32)f2bf(v.w) << 16));
      *reinterpret_cast<uint2*>(reinterpret_cast<char*>(Bs) + byte) = p;
    }
    __syncthreads();
#pragma unroll
    for (int kf = 0; kf < 2; ++kf) {
      int kb = kf * 64 + lk * 16;
      bf16x8 a[4], b[4];
#pragma unroll
      for (int m = 0; m < 4; ++m) {
        int row = wr * 64 + m * 16 + lr;
        a[m] = *reinterpret_cast<bf16x8*>(reinterpret_cast<char*>(As) + ((row * 128 + kb) ^ ((row & 7) << 4)));
      }
#pragma unroll
      for (int n = 0; n < 4; ++n) {
        int row = wc * 64 + n * 16 + lr;
        b[n] = *reinterpret_cast<bf16x8*>(reinterpret_cast<char*>(Bs) + ((row * 128 + kb) ^ ((row & 7) << 4)));
      }
#pragma unroll
      for (int m = 0; m < 4; ++m)
#pragma unroll
        for (int n = 0; n < 4; ++n)
          acc[m][n] = __builtin_amdgcn_mfma_f32_16x16x32_bf16(a[m], b[n], acc[m][n], 0, 0, 0);
    }
  }
#pragma unroll
  for (int m = 0; m < 4; ++m)
#pragma unroll
    for (int n = 0; n < 4; ++n)
#pragma unroll
      for (int i = 0; i < 4; ++i) {
        int row = wr * 64 + m * 16 + lk * 4 + i;
        if (row < cnt) {
          int col = n0 + wc * 64 + n * 16 + lr;
          float v = acc[m][n][i] * wts[row];
          atomicAdd(&y[(size_t)toks[row] * HID + col], v);
        }
      }
}

extern "C" void kernel_launch(void* const* d_in, const int* in_sizes, int n_in,
                              void* d_out, int out_size, void* d_ws, size_t ws_size,
                              hipStream_t stream) {
  const float* x = (const float*)d_in[0];
  const float* gw = (const float*)d_in[1];
  const float* wgu = (const float*)d_in[2];
  const float* wd = (const float*)d_in[3];
  const float* sim = (const float*)d_in[4];
  float* y = (float*)d_out;

  char* ws = (char*)d_ws;
  size_t off = 0;
  auto alloc = [&](size_t bytes) {
    char* p = ws + off;
    off += (bytes + 255) & ~(size_t)255;
    return p;
  };
  u16* xb = (u16*)alloc((size_t)NTOK * HID * 2);
  u16* h_perm = (u16*)alloc((size_t)NSLOT * DFF * 2);
  int* slot_e = (int*)alloc(NSLOT * 4);
  float* slot_w = (float*)alloc(NSLOT * 4);
  int* perm_token = (int*)alloc(NSLOT * 4);
  float* perm_w = (float*)alloc(NSLOT * 4);
  int* inv = (int*)alloc(NSLOT * 4);
  int* blockCounts = (int*)alloc(NE * NB * 4);
  int* startEB = (int*)alloc(NE * NB * 4);
  int* tile_e = (int*)alloc(MAX_TILES * 4);
  int* tile_row0 = (int*)alloc(MAX_TILES * 4);
  int* tile_cnt = (int*)alloc(MAX_TILES * 4);
  int* tileCount = (int*)alloc(4);
  size_t off_common = off;
  if (off_common > ws_size) return;

  // full-path extras: bf16 weights + fp16 per-slot down output (aliased over wgu_b)
  size_t wgu_elems = (size_t)NE * 2 * DFF * HID;
  size_t wd_elems = (size_t)NE * HID * DFF;
  size_t region_bytes = (size_t)NSLOT * HID * 2;  // yp (268MB) > wgu_b (201MB)
  u16* wd_b = (u16*)alloc(wd_elems * 2);
  char* region = alloc(region_bytes);
  u16* wgu_b = (u16*)region;
  _Float16* yp = (_Float16*)region;
  bool full = (off <= ws_size);

  // common: router + sort
  convertf2b_kernel<<<2048, 256, 0, stream>>>(x, xb, NTOK * HID / 4);
  router_kernel<<<NTOK, 256, 0, stream>>>(x, gw, sim, slot_e, slot_w);
  hist_kernel<<<NB, 256, 0, stream>>>(slot_e, blockCounts);
  scan_kernel<<<1, 64, 0, stream>>>(blockCounts, startEB, tile_e, tile_row0, tile_cnt, tileCount);
  place_kernel<<<NB, 64, 0, stream>>>(slot_e, slot_w, startEB, perm_token, perm_w, inv);

  if (full) {
    convertf2b_kernel<<<4096, 256, 0, stream>>>(wgu, wgu_b, (int)(wgu_elems / 4));
    convertf2b_kernel<<<4096, 256, 0, stream>>>(wd, wd_b, (int)(wd_elems / 4));
    gu_fast<<<dim3(MAX_TILES, DFF / 64), 256, 0, stream>>>(
        xb, wgu_b, perm_token, tile_e, tile_row0, tile_cnt, tileCount, h_perm);
    down_fast<<<dim3(MAX_TILES, HID / 128), 256, 0, stream>>>(
        h_perm, wd_b, perm_w, tile_e, tile_row0, tile_cnt, tileCount, yp);
    reduce_kernel<<<NTOK, 256, 0, stream>>>(yp, inv, y);
  } else {
    hipMemsetAsync(d_out, 0, (size_t)NTOK * HID * sizeof(float), stream);
    gu_legacy<<<dim3(MAX_TILES, DFF / 64), 256, 0, stream>>>(
        xb, wgu, perm_token, tile_e, tile_row0, tile_cnt, tileCount, h_perm);
    down_legacy<<<dim3(MAX_TILES, HID / 128), 256, 0, stream>>>(
        h_perm, wd, perm_token, perm_w, tile_e, tile_row0, tile_cnt, tileCount, y);
  }
}

// Round 3
// 1582.288 us; speedup vs baseline: 1.3058x; 1.0038x over previous
//
#include <hip/hip_runtime.h>
#include <stdint.h>
#include <string.h>

#define NTOK 8192
#define HID 2048
#define NE 32
#define DFF 768
#define NSLOT 65536
#define NB 256
#define MT 128
#define MAX_TILES 544   // 65536/128 + 32

typedef unsigned short u16;
typedef unsigned int u32;

using f32x4 = __attribute__((ext_vector_type(4))) float;
using bf16x8 = __attribute__((ext_vector_type(8))) short;

static __device__ __forceinline__ u16 f2bf(float f) {
  u32 x = __float_as_uint(f);
  x += 0x7fffu + ((x >> 16) & 1u);
  return (u16)(x >> 16);
}

typedef const __attribute__((address_space(1))) unsigned int* gp_t;
typedef __attribute__((address_space(3))) unsigned int* lp_t;
static __device__ __forceinline__ void gload16(const void* g, void* l) {
  __builtin_amdgcn_global_load_lds((gp_t)g, (lp_t)l, 16, 0, 0);
}

// ---------------- fp32 -> bf16 convert (weights) ----------------
__global__ void convertf2b_kernel(const float* __restrict__ src, u16* __restrict__ dst, int n4) {
  int i = blockIdx.x * blockDim.x + threadIdx.x;
  int stride = gridDim.x * blockDim.x;
  for (; i < n4; i += stride) {
    float4 v = reinterpret_cast<const float4*>(src)[i];
    u32 lo = (u32)f2bf(v.x) | ((u32)f2bf(v.y) << 16);
    u32 hi = (u32)f2bf(v.z) | ((u32)f2bf(v.w) << 16);
    reinterpret_cast<uint2*>(dst)[i] = make_uint2(lo, hi);
  }
}

// ---------------- router: logits + softmax + top8 + reroute (+ x->bf16) ----------------
__global__ void router_kernel(const float* __restrict__ x, const float* __restrict__ gw,
                              const float* __restrict__ sim,
                              int* __restrict__ slot_e, float* __restrict__ slot_w,
                              u16* __restrict__ xb) {
  int t = blockIdx.x;
  __shared__ float xs[HID];
  __shared__ float logits[NE];
  const float* xr = x + (size_t)t * HID;
  for (int i = threadIdx.x; i < HID / 4; i += 256)
    reinterpret_cast<float4*>(xs)[i] = reinterpret_cast<const float4*>(xr)[i];
  __syncthreads();
  // emit bf16 copy of this row (one 16B chunk per thread)
  {
    int i = threadIdx.x;  // HID/8 == 256
    float4 v0 = reinterpret_cast<float4*>(xs)[i * 2];
    float4 v1 = reinterpret_cast<float4*>(xs)[i * 2 + 1];
    uint4 o;
    o.x = (u32)f2bf(v0.x) | ((u32)f2bf(v0.y) << 16);
    o.y = (u32)f2bf(v0.z) | ((u32)f2bf(v0.w) << 16);
    o.z = (u32)f2bf(v1.x) | ((u32)f2bf(v1.y) << 16);
    o.w = (u32)f2bf(v1.z) | ((u32)f2bf(v1.w) << 16);
    reinterpret_cast<uint4*>(xb + (size_t)t * HID)[i] = o;
  }
  int e = threadIdx.x >> 3, part = threadIdx.x & 7;
  const float4* wv = reinterpret_cast<const float4*>(gw + (size_t)e * HID + part * 256);
  const float4* xv = reinterpret_cast<const float4*>(xs + part * 256);
  float s = 0.f;
#pragma unroll
  for (int j = 0; j < 64; ++j) {
    float4 a = xv[j], b = wv[j];
    s += a.x * b.x + a.y * b.y + a.z * b.z + a.w * b.w;
  }
  s += __shfl_xor(s, 1); s += __shfl_xor(s, 2); s += __shfl_xor(s, 4);
  if (part == 0) logits[e] = s;
  __syncthreads();
  if (threadIdx.x == 0) {
    float l[NE];
#pragma unroll
    for (int i = 0; i < NE; ++i) l[i] = logits[i];
    unsigned mask = 0;
    int idx[8]; float lv[8];
#pragma unroll
    for (int k = 0; k < 8; ++k) {
      float best = -3.4e38f; int bi = 0;
#pragma unroll
      for (int i = 0; i < NE; ++i) {
        bool ok = (((mask >> i) & 1u) == 0u) && (l[i] > best);
        best = ok ? l[i] : best;
        bi = ok ? i : bi;
      }
      idx[k] = bi; lv[k] = best; mask |= (1u << bi);
    }
    float w[8]; float ssum = 0.f;
#pragma unroll
    for (int k = 0; k < 8; ++k) { w[k] = __expf(lv[k] - lv[0]); ssum += w[k]; }
    float inv = 1.f / ssum;
    int base = t * 8;
#pragma unroll
    for (int i = 0; i < 4; ++i) { slot_e[base + i] = idx[i]; slot_w[base + i] = w[i] * inv; }
#pragma unroll
    for (int j = 0; j < 4; ++j) {
      int sj = idx[4 + j];
      float best = -2.f; int bsel = idx[0];
#pragma unroll
      for (int i = 0; i < 4; ++i) {
        int pe = idx[i];
        float sv = sim[sj * NE + pe];
        bool ok = sv > best;
        best = ok ? sv : best;
        bsel = ok ? pe : bsel;
      }
      int ns = (best < 0.5f) ? sj : bsel;
      slot_e[base + 4 + j] = ns; slot_w[base + 4 + j] = w[4 + j] * inv;
    }
  }
}

// ---------------- counting sort: hist / scan / place ----------------
__global__ void hist_kernel(const int* __restrict__ slot_e, int* __restrict__ blockCounts) {
  __shared__ int cnt[NE];
  if (threadIdx.x < NE) cnt[threadIdx.x] = 0;
  __syncthreads();
  int i = blockIdx.x * 256 + threadIdx.x;
  atomicAdd(&cnt[slot_e[i]], 1);
  __syncthreads();
  if (threadIdx.x < NE) blockCounts[threadIdx.x * NB + blockIdx.x] = cnt[threadIdx.x];
}

__global__ void scan_kernel(const int* __restrict__ blockCounts, int* __restrict__ startEB,
                            int* __restrict__ tile_e, int* __restrict__ tile_row0,
                            int* __restrict__ tile_cnt, int* __restrict__ tileCount) {
  __shared__ int totals[NE];
  __shared__ int bases[NE];
  int t = threadIdx.x;
  if (t < NE) {
    int run = 0;
    for (int b = 0; b < NB; ++b) run += blockCounts[t * NB + b];
    totals[t] = run;
  }
  __syncthreads();
  if (t == 0) {
    int base = 0, nt = 0;
    for (int e = 0; e < NE; ++e) {
      bases[e] = base;
      int tot = totals[e];
      for (int i = 0; i < tot; i += MT) {
        tile_e[nt] = e;
        tile_row0[nt] = base + i;
        tile_cnt[nt] = (tot - i < MT) ? (tot - i) : MT;
        ++nt;
      }
      base += tot;
    }
    *tileCount = nt;
  }
  __syncthreads();
  if (t < NE) {
    int run = bases[t];
    for (int b = 0; b < NB; ++b) {
      startEB[t * NB + b] = run;
      run += blockCounts[t * NB + b];
    }
  }
}

__global__ void place_kernel(const int* __restrict__ slot_e, const float* __restrict__ slot_w,
                             const int* __restrict__ startEB,
                             int* __restrict__ perm_token, float* __restrict__ perm_w,
                             int* __restrict__ inv) {
  __shared__ int se[256];
  __shared__ float sw[256];
  int b = blockIdx.x;
  for (int i = threadIdx.x; i < 256; i += 64) {
    se[i] = slot_e[b * 256 + i];
    sw[i] = slot_w[b * 256 + i];
  }
  __syncthreads();
  int e = threadIdx.x;
  if (e < NE) {
    int pos = startEB[e * NB + b];
    for (int i = 0; i < 256; ++i) {
      if (se[i] == e) {
        perm_token[pos] = (b * 256 + i) >> 3;
        perm_w[pos] = sw[i];
        inv[b * 256 + i] = pos;
        ++pos;
      }
    }
  }
}

// ---------------- gate_up GEMM: 2-phase prefetch dbuf, grid (nblk, tile) ----------------
__global__ __launch_bounds__(256) void gu_fast(
    const u16* __restrict__ xb, const u16* __restrict__ wgub,
    const int* __restrict__ perm_token,
    const int* __restrict__ tile_e, const int* __restrict__ tile_row0,
    const int* __restrict__ tile_cnt, const int* __restrict__ tileCount,
    u16* __restrict__ h_perm) {
  int tile = blockIdx.y;
  if (tile >= *tileCount) return;
  int e = tile_e[tile], row0 = tile_row0[tile], cnt = tile_cnt[tile];
  int n0 = blockIdx.x * 64;
  __shared__ __align__(16) u16 As[2][MT * 64];   // XOR-swizzled via source
  __shared__ __align__(16) u16 Bs[2][MT * 64];   // rows 0-63 gate, 64-127 up
  __shared__ int toks[MT];
  if (threadIdx.x < MT) {
    int idx = row0 + (int)threadIdx.x;
    if (idx > NSLOT - 1) idx = NSLOT - 1;
    toks[threadIdx.x] = perm_token[idx];
  }
  int wave = threadIdx.x >> 6, lane = threadIdx.x & 63;
  int wr = wave >> 1, wc = wave & 1;
  int lr = lane & 15, lk = lane >> 4;
  f32x4 zero = {0.f, 0.f, 0.f, 0.f};
  f32x4 accg[4][2], accu[4][2];
#pragma unroll
  for (int m = 0; m < 4; ++m)
#pragma unroll
    for (int n = 0; n < 2; ++n) { accg[m][n] = zero; accu[m][n] = zero; }

  const u16* wgb = wgub + (size_t)e * (2 * DFF) * HID;
  int r_ = (wave * 64 + lane) >> 3;          // base LDS row for issue i=0
  int c_ = lane & 7;

  auto stage = [&](int kt, int buf) {
#pragma unroll
    for (int i = 0; i < 4; ++i) {
      int r = r_ + i * 32;
      int j = c_ ^ (r & 7);
      gload16(xb + (size_t)toks[r] * HID + kt + j * 8, (char*)As[buf] + (i * 4 + wave) * 1024);
    }
#pragma unroll
    for (int i = 0; i < 4; ++i) {
      int r = r_ + i * 32;
      int j = c_ ^ (r & 7);
      int wrow = (r < 64) ? (n0 + r) : (DFF + n0 + (r - 64));
      gload16(wgb + (size_t)wrow * HID + kt + j * 8, (char*)Bs[buf] + (i * 4 + wave) * 1024);
    }
  };

  __syncthreads();            // toks ready
  stage(0, 0);
  __syncthreads();            // drains vmcnt: buf0 ready
  int cur = 0;
  const int NK = HID / 64;    // 32
  for (int kti = 0; kti < NK; ++kti) {
    if (kti + 1 < NK) stage((kti + 1) * 64, cur ^ 1);   // prefetch next under compute
    char* Ab = (char*)As[cur];
    char* Bb = (char*)Bs[cur];
#pragma unroll
    for (int kf = 0; kf < 2; ++kf) {
      int kb = kf * 64 + lk * 16;
      bf16x8 a[4], bg2[2], bu2[2];
#pragma unroll
      for (int m = 0; m < 4; ++m) {
        int row = wr * 64 + m * 16 + lr;
        a[m] = *reinterpret_cast<bf16x8*>(Ab + ((row * 128 + kb) ^ ((row & 7) << 4)));
      }
#pragma unroll
      for (int n = 0; n < 2; ++n) {
        int rg = wc * 32 + n * 16 + lr;
        int ru = 64 + rg;
        bg2[n] = *reinterpret_cast<bf16x8*>(Bb + ((rg * 128 + kb) ^ ((rg & 7) << 4)));
        bu2[n] = *reinterpret_cast<bf16x8*>(Bb + ((ru * 128 + kb) ^ ((ru & 7) << 4)));
      }
#pragma unroll
      for (int m = 0; m < 4; ++m)
#pragma unroll
        for (int n = 0; n < 2; ++n) {
          accg[m][n] = __builtin_amdgcn_mfma_f32_16x16x32_bf16(a[m], bg2[n], accg[m][n], 0, 0, 0);
          accu[m][n] = __builtin_amdgcn_mfma_f32_16x16x32_bf16(a[m], bu2[n], accu[m][n], 0, 0, 0);
        }
    }
    __syncthreads();          // drains vmcnt: next buffer staged, reads done
    cur ^= 1;
  }
#pragma unroll
  for (int m = 0; m < 4; ++m)
#pragma unroll
    for (int n = 0; n < 2; ++n)
#pragma unroll
      for (int i = 0; i < 4; ++i) {
        int row = wr * 64 + m * 16 + lk * 4 + i;
        if (row < cnt) {
          int col = n0 + wc * 32 + n * 16 + lr;
          float g = accg[m][n][i], u = accu[m][n][i];
          float h = g / (1.f + __expf(-g)) * u;
          h_perm[(size_t)(row0 + row) * DFF + col] = f2bf(h);
        }
      }
}

// ---------------- down GEMM -> yp (fp16), 2-phase prefetch dbuf ----------------
__global__ __launch_bounds__(256) void down_fast(
    const u16* __restrict__ h_perm, const u16* __restrict__ wdb,
    const float* __restrict__ perm_w,
    const int* __restrict__ tile_e, const int* __restrict__ tile_row0,
    const int* __restrict__ tile_cnt, const int* __restrict__ tileCount,
    _Float16* __restrict__ yp) {
  int tile = blockIdx.y;
  if (tile >= *tileCount) return;
  int e = tile_e[tile], row0 = tile_row0[tile], cnt = tile_cnt[tile];
  int n0 = blockIdx.x * 128;
  __shared__ __align__(16) u16 As[2][MT * 64];
  __shared__ __align__(16) u16 Bs[2][MT * 64];
  __shared__ float wts[MT];
  if (threadIdx.x < MT) {
    int idx = row0 + (int)threadIdx.x;
    if (idx > NSLOT - 1) idx = NSLOT - 1;
    wts[threadIdx.x] = perm_w[idx];
  }
  int wave = threadIdx.x >> 6, lane = threadIdx.x & 63;
  int wr = wave >> 1, wc = wave & 1;
  int lr = lane & 15, lk = lane >> 4;
  f32x4 zero = {0.f, 0.f, 0.f, 0.f};
  f32x4 acc[4][4];
#pragma unroll
  for (int m = 0; m < 4; ++m)
#pragma unroll
    for (int n = 0; n < 4; ++n) acc[m][n] = zero;

  const u16* wb = wdb + (size_t)e * HID * DFF;
  int r_ = (wave * 64 + lane) >> 3;
  int c_ = lane & 7;
  int arow0 = row0 + r_;

  auto stage = [&](int kt, int buf) {
#pragma unroll
    for (int i = 0; i < 4; ++i) {
      int r = r_ + i * 32;
      int j = c_ ^ (r & 7);
      int idx = arow0 + i * 32;
      if (idx > NSLOT - 1) idx = NSLOT - 1;
      gload16(h_perm + (size_t)idx * DFF + kt + j * 8, (char*)As[buf] + (i * 4 + wave) * 1024);
    }
#pragma unroll
    for (int i = 0; i < 4; ++i) {
      int r = r_ + i * 32;
      int j = c_ ^ (r & 7);
      gload16(wb + (size_t)(n0 + r) * DFF + kt + j * 8, (char*)Bs[buf] + (i * 4 + wave) * 1024);
    }
  };

  __syncthreads();
  stage(0, 0);
  __syncthreads();
  int cur = 0;
  const int NK = DFF / 64;    // 12
  for (int kti = 0; kti < NK; ++kti) {
    if (kti + 1 < NK) stage((kti + 1) * 64, cur ^ 1);
    char* Ab = (char*)As[cur];
    char* Bb = (char*)Bs[cur];
#pragma unroll
    for (int kf = 0; kf < 2; ++kf) {
      int kb = kf * 64 + lk * 16;
      bf16x8 a[4], b[4];
#pragma unroll
      for (int m = 0; m < 4; ++m) {
        int row = wr * 64 + m * 16 + lr;
        a[m] = *reinterpret_cast<bf16x8*>(Ab + ((row * 128 + kb) ^ ((row & 7) << 4)));
      }
#pragma unroll
      for (int n = 0; n < 4; ++n) {
        int row = wc * 64 + n * 16 + lr;
        b[n] = *reinterpret_cast<bf16x8*>(Bb + ((row * 128 + kb) ^ ((row & 7) << 4)));
      }
#pragma unroll
      for (int m = 0; m < 4; ++m)
#pragma unroll
        for (int n = 0; n < 4; ++n)
          acc[m][n] = __builtin_amdgcn_mfma_f32_16x16x32_bf16(a[m], b[n], acc[m][n], 0, 0, 0);
    }
    __syncthreads();
    cur ^= 1;
  }
#pragma unroll
  for (int m = 0; m < 4; ++m)
#pragma unroll
    for (int n = 0; n < 4; ++n)
#pragma unroll
      for (int i = 0; i < 4; ++i) {
        int row = wr * 64 + m * 16 + lk * 4 + i;
        if (row < cnt) {
          int col = n0 + wc * 64 + n * 16 + lr;
          yp[(size_t)(row0 + row) * HID + col] = (_Float16)(acc[m][n][i] * wts[row]);
        }
      }
}

// ---------------- per-token gather-reduce of 8 slots ----------------
__global__ void reduce_kernel(const _Float16* __restrict__ yp, const int* __restrict__ inv,
                              float* __restrict__ y) {
  int t = blockIdx.x;
  __shared__ int pos[8];
  if (threadIdx.x < 8) pos[threadIdx.x] = inv[t * 8 + threadIdx.x];
  __syncthreads();
  int c = threadIdx.x * 8;
  float s[8] = {0.f, 0.f, 0.f, 0.f, 0.f, 0.f, 0.f, 0.f};
#pragma unroll
  for (int j = 0; j < 8; ++j) {
    uint4 v = *reinterpret_cast<const uint4*>(yp + (size_t)pos[j] * HID + c);
    const u16* p = reinterpret_cast<const u16*>(&v);
#pragma unroll
    for (int k = 0; k < 8; ++k) {
      _Float16 h;
      u16 us = p[k];
      __builtin_memcpy(&h, &us, 2);
      s[k] += (float)h;
    }
  }
  float* yo = y + (size_t)t * HID + c;
  float4 o0 = {s[0], s[1], s[2], s[3]};
  float4 o1 = {s[4], s[5], s[6], s[7]};
  *reinterpret_cast<float4*>(yo) = o0;
  *reinterpret_cast<float4*>(yo + 4) = o1;
}

// ================= legacy fallback (ws too small): round-1 style =================
__global__ __launch_bounds__(256, 2) void gu_legacy(
    const u16* __restrict__ xb, const float* __restrict__ wgu,
    const int* __restrict__ perm_token,
    const int* __restrict__ tile_e, const int* __restrict__ tile_row0,
    const int* __restrict__ tile_cnt, const int* __restrict__ tileCount,
    u16* __restrict__ h_perm) {
  int tile = blockIdx.x;
  if (tile >= *tileCount) return;
  int e = tile_e[tile], row0 = tile_row0[tile], cnt = tile_cnt[tile];
  int n0 = blockIdx.y * 64;
  __shared__ __align__(16) u16 As[MT * 64];
  __shared__ __align__(16) u16 Bg[64 * 64];
  __shared__ __align__(16) u16 Bu[64 * 64];
  __shared__ int toks[MT];
  if (threadIdx.x < MT) {
    int idx = row0 + (int)threadIdx.x;
    if (idx > NSLOT - 1) idx = NSLOT - 1;
    toks[threadIdx.x] = perm_token[idx];
  }
  int wave = threadIdx.x >> 6, lane = threadIdx.x & 63;
  int wr = wave >> 1, wc = wave & 1;
  int lr = lane & 15, lk = lane >> 4;
  f32x4 zero = {0.f, 0.f, 0.f, 0.f};
  f32x4 accg[4][2], accu[4][2];
#pragma unroll
  for (int m = 0; m < 4; ++m)
#pragma unroll
    for (int n = 0; n < 2; ++n) { accg[m][n] = zero; accu[m][n] = zero; }
  int achunk = threadIdx.x & 7, arow = threadIdx.x >> 3;
  int bfc = threadIdx.x & 15, brow = threadIdx.x >> 4;
  const float* wbaseg = wgu + (size_t)e * (2 * DFF) * HID + (size_t)n0 * HID;
  const float* wbaseu = wbaseg + (size_t)DFF * HID;
  for (int kt = 0; kt < HID; kt += 64) {
    __syncthreads();
#pragma unroll
    for (int g = 0; g < 4; ++g) {
      int r = g * 32 + arow;
      const u16* src = xb + (size_t)toks[r] * HID + kt + achunk * 8;
      uint4 v = *reinterpret_cast<const uint4*>(src);
      int byte = (r * 128 + achunk * 16) ^ ((r & 7) << 4);
      *reinterpret_cast<uint4*>(reinterpret_cast<char*>(As) + byte) = v;
    }
#pragma unroll
    for (int g = 0; g < 4; ++g) {
      int r = g * 16 + brow;
      float4 vg = *reinterpret_cast<const float4*>(wbaseg + (size_t)r * HID + kt + bfc * 4);
      float4 vu = *reinterpret_cast<const float4*>(wbaseu + (size_t)r * HID + kt + bfc * 4);
      int byte = (r * 128 + bfc * 8) ^ ((r & 7) << 4);
      uint2 pg = make_uint2((u32)f2bf(vg.x) | ((u32)f2bf(vg.y) << 16),
                            (u32)f2bf(vg.z) | ((u32)f2bf(vg.w) << 16));
      uint2 pu = make_uint2((u32)f2bf(vu.x) | ((u32)f2bf(vu.y) << 16),
                            (u32)f2bf(vu.z) | ((u32)f2bf(vu.w) << 16));
      *reinterpret_cast<uint2*>(reinterpret_cast<char*>(Bg) + byte) = pg;
      *reinterpret_cast<uint2*>(reinterpret_cast<char*>(Bu) + byte) = pu;
    }
    __syncthreads();
#pragma unroll
    for (int kf = 0; kf < 2; ++kf) {
      int kb = kf * 64 + lk * 16;
      bf16x8 a[4], bg2[2], bu2[2];
#pragma unroll
      for (int m = 0; m < 4; ++m) {
        int row = wr * 64 + m * 16 + lr;
        a[m] = *reinterpret_cast<bf16x8*>(reinterpret_cast<char*>(As) + ((row * 128 + kb) ^ ((row & 7) << 4)));
      }
#pragma unroll
      for (int n = 0; n < 2; ++n) {
        int row = wc * 32 + n * 16 + lr;
        int byte = (row * 128 + kb) ^ ((row & 7) << 4);
        bg2[n] = *reinterpret_cast<bf16x8*>(reinterpret_cast<char*>(Bg) + byte);
        bu2[n] = *reinterpret_cast<bf16x8*>(reinterpret_cast<char*>(Bu) + byte);
      }
#pragma unroll
      for (int m = 0; m < 4; ++m)
#pragma unroll
        for (int n = 0; n < 2; ++n) {
          accg[m][n] = __builtin_amdgcn_mfma_f32_16x16x32_bf16(a[m], bg2[n], accg[m][n], 0, 0, 0);
          accu[m][n] = __builtin_amdgcn_mfma_f32_16x16x32_bf16(a[m], bu2[n], accu[m][n], 0, 0, 0);
        }
    }
  }
#pragma unroll
  for (int m = 0; m < 4; ++m)
#pragma unroll
    for (int n = 0; n < 2; ++n)
#pragma unroll
      for (int i = 0; i < 4; ++i) {
        int row = wr * 64 + m * 16 + lk * 4 + i;
        if (row < cnt) {
          int col = n0 + wc * 32 + n * 16 + lr;
          float g = accg[m][n][i], u = accu[m][n][i];
          float h = g / (1.f + __expf(-g)) * u;
          h_perm[(size_t)(row0 + row) * DFF + col] = f2bf(h);
        }
      }
}

__global__ __launch_bounds__(256, 2) void down_legacy(
    const u16* __restrict__ h_perm, const float* __restrict__ wd,
    const int* __restrict__ perm_token, const float* __restrict__ perm_w,
    const int* __restrict__ tile_e, const int* __restrict__ tile_row0,
    const int* __restrict__ tile_cnt, const int* __restrict__ tileCount,
    float* __restrict__ y) {
  int tile = blockIdx.x;
  if (tile >= *tileCount) return;
  int e = tile_e[tile], row0 = tile_row0[tile], cnt = tile_cnt[tile];
  int n0 = blockIdx.y * 128;
  __shared__ __align__(16) u16 As[MT * 64];
  __shared__ __align__(16) u16 Bs[MT * 64];
  __shared__ int toks[MT];
  __shared__ float wts[MT];
  if (threadIdx.x < MT) {
    int idx = row0 + (int)threadIdx.x;
    if (idx > NSLOT - 1) idx = NSLOT - 1;
    toks[threadIdx.x] = perm_token[idx];
    wts[threadIdx.x] = perm_w[idx];
  }
  int wave = threadIdx.x >> 6, lane = threadIdx.x & 63;
  int wr = wave >> 1, wc = wave & 1;
  int lr = lane & 15, lk = lane >> 4;
  f32x4 zero = {0.f, 0.f, 0.f, 0.f};
  f32x4 acc[4][4];
#pragma unroll
  for (int m = 0; m < 4; ++m)
#pragma unroll
    for (int n = 0; n < 4; ++n) acc[m][n] = zero;
  int achunk = threadIdx.x & 7, arow = threadIdx.x >> 3;
  int bfc = threadIdx.x & 15, brow = threadIdx.x >> 4;
  const float* wbase = wd + (size_t)e * HID * DFF + (size_t)n0 * DFF;
  for (int kt = 0; kt < DFF; kt += 64) {
    __syncthreads();
#pragma unroll
    for (int g = 0; g < 4; ++g) {
      int r = g * 32 + arow;
      int idx = row0 + r;
      if (idx > NSLOT - 1) idx = NSLOT - 1;
      const u16* src = h_perm + (size_t)idx * DFF + kt + achunk * 8;
      uint4 v = *reinterpret_cast<const uint4*>(src);
      int byte = (r * 128 + achunk * 16) ^ ((r & 7) << 4);
      *reinterpret_cast<uint4*>(reinterpret_cast<char*>(As) + byte) = v;
    }
#pragma unroll
    for (int g = 0; g < 8; ++g) {
      int r = g * 16 + brow;
      float4 v = *reinterpret_cast<const float4*>(wbase + (size_t)r * DFF + kt + bfc * 4);
      int byte = (r * 128 + bfc * 8) ^ ((r & 7) << 4);
      uint2 p = make_uint2((u32)f2bf(v.x) | ((u32)f2bf(v.y) << 16),
                           (u32)f2bf(v.z) | ((u32)f2bf(v.w) << 16));
      *reinterpret_cast<uint2*>(reinterpret_cast<char*>(Bs) + byte) = p;
    }
    __syncthreads();
#pragma unroll
    for (int kf = 0; kf < 2; ++kf) {
      int kb = kf * 64 + lk * 16;
      bf16x8 a[4], b[4];
#pragma unroll
      for (int m = 0; m < 4; ++m) {
        int row = wr * 64 + m * 16 + lr;
        a[m] = *reinterpret_cast<bf16x8*>(reinterpret_cast<char*>(As) + ((row * 128 + kb) ^ ((row & 7) << 4)));
      }
#pragma unroll
      for (int n = 0; n < 4; ++n) {
        int row = wc * 64 + n * 16 + lr;
        b[n] = *reinterpret_cast<bf16x8*>(reinterpret_cast<char*>(Bs) + ((row * 128 + kb) ^ ((row & 7) << 4)));
      }
#pragma unroll
      for (int m = 0; m < 4; ++m)
#pragma unroll
        for (int n = 0; n < 4; ++n)
          acc[m][n] = __builtin_amdgcn_mfma_f32_16x16x32_bf16(a[m], b[n], acc[m][n], 0, 0, 0);
    }
  }
#pragma unroll
  for (int m = 0; m < 4; ++m)
#pragma unroll
    for (int n = 0; n < 4; ++n)
#pragma unroll
      for (int i = 0; i < 4; ++i) {
        int row = wr * 64 + m * 16 + lk * 4 + i;
        if (row < cnt) {
          int col = n0 + wc * 64 + n * 16 + lr;
          float v = acc[m][n][i] * wts[row];
          atomicAdd(&y[(size_t)toks[row] * HID + col], v);
        }
      }
}

extern "C" void kernel_launch(void* const* d_in, const int* in_sizes, int n_in,
                              void* d_out, int out_size, void* d_ws, size_t ws_size,
                              hipStream_t stream) {
  const float* x = (const float*)d_in[0];
  const float* gw = (const float*)d_in[1];
  const float* wgu = (const float*)d_in[2];
  const float* wd = (const float*)d_in[3];
  const float* sim = (const float*)d_in[4];
  float* y = (float*)d_out;

  char* ws = (char*)d_ws;
  size_t off = 0;
  auto alloc = [&](size_t bytes) {
    char* p = ws + off;
    off += (bytes + 255) & ~(size_t)255;
    return p;
  };
  u16* xb = (u16*)alloc((size_t)NTOK * HID * 2);
  u16* h_perm = (u16*)alloc((size_t)NSLOT * DFF * 2);
  int* slot_e = (int*)alloc(NSLOT * 4);
  float* slot_w = (float*)alloc(NSLOT * 4);
  int* perm_token = (int*)alloc(NSLOT * 4);
  float* perm_w = (float*)alloc(NSLOT * 4);
  int* inv = (int*)alloc(NSLOT * 4);
  int* blockCounts = (int*)alloc(NE * NB * 4);
  int* startEB = (int*)alloc(NE * NB * 4);
  int* tile_e = (int*)alloc(MAX_TILES * 4);
  int* tile_row0 = (int*)alloc(MAX_TILES * 4);
  int* tile_cnt = (int*)alloc(MAX_TILES * 4);
  int* tileCount = (int*)alloc(4);
  size_t off_common = off;
  if (off_common > ws_size) return;

  // full-path extras: bf16 weights + fp16 per-slot down output (aliased over wgu_b)
  size_t wgu_elems = (size_t)NE * 2 * DFF * HID;
  size_t wd_elems = (size_t)NE * HID * DFF;
  size_t region_bytes = (size_t)NSLOT * HID * 2;  // yp (268MB) > wgu_b (201MB)
  u16* wd_b = (u16*)alloc(wd_elems * 2);
  char* region = alloc(region_bytes);
  u16* wgu_b = (u16*)region;
  _Float16* yp = (_Float16*)region;
  bool full = (off <= ws_size);

  // common: router (+x->bf16) + sort
  router_kernel<<<NTOK, 256, 0, stream>>>(x, gw, sim, slot_e, slot_w, xb);
  hist_kernel<<<NB, 256, 0, stream>>>(slot_e, blockCounts);
  scan_kernel<<<1, 64, 0, stream>>>(blockCounts, startEB, tile_e, tile_row0, tile_cnt, tileCount);
  place_kernel<<<NB, 64, 0, stream>>>(slot_e, slot_w, startEB, perm_token, perm_w, inv);

  if (full) {
    convertf2b_kernel<<<4096, 256, 0, stream>>>(wgu, wgu_b, (int)(wgu_elems / 4));
    convertf2b_kernel<<<4096, 256, 0, stream>>>(wd, wd_b, (int)(wd_elems / 4));
    gu_fast<<<dim3(DFF / 64, MAX_TILES), 256, 0, stream>>>(
        xb, wgu_b, perm_token, tile_e, tile_row0, tile_cnt, tileCount, h_perm);
    down_fast<<<dim3(HID / 128, MAX_TILES), 256, 0, stream>>>(
        h_perm, wd_b, perm_w, tile_e, tile_row0, tile_cnt, tileCount, yp);
    reduce_kernel<<<NTOK, 256, 0, stream>>>(yp, inv, y);
  } else {
    hipMemsetAsync(d_out, 0, (size_t)NTOK * HID * sizeof(float), stream);
    gu_legacy<<<dim3(MAX_TILES, DFF / 64), 256, 0, stream>>>(
        xb, wgu, perm_token, tile_e, tile_row0, tile_cnt, tileCount, h_perm);
    down_legacy<<<dim3(MAX_TILES, HID / 128), 256, 0, stream>>>(
        h_perm, wd, perm_token, perm_w, tile_e, tile_row0, tile_cnt, tileCount, y);
  }
}

// Round 4
// 1453.646 us; speedup vs baseline: 1.4214x; 1.0885x over previous
//
#include <hip/hip_runtime.h>
#include <stdint.h>
#include <string.h>

#define NTOK 8192
#define HID 2048
#define NE 32
#define DFF 768
#define NSLOT 65536
#define NB 256
#define MT 128
#define MAX_TILES 544   // 65536/128 + 32

typedef unsigned short u16;
typedef unsigned int u32;

using f32x4 = __attribute__((ext_vector_type(4))) float;
using bf16x8 = __attribute__((ext_vector_type(8))) short;

static __device__ __forceinline__ u16 f2bf(float f) {
  u32 x = __float_as_uint(f);
  x += 0x7fffu + ((x >> 16) & 1u);
  return (u16)(x >> 16);
}

typedef const __attribute__((address_space(1))) unsigned int* gp_t;
typedef __attribute__((address_space(3))) unsigned int* lp_t;
static __device__ __forceinline__ void gload16(const void* g, void* l) {
  __builtin_amdgcn_global_load_lds((gp_t)g, (lp_t)l, 16, 0, 0);
}

// ---------------- fp32 -> bf16 convert (weights) ----------------
__global__ void convertf2b_kernel(const float* __restrict__ src, u16* __restrict__ dst, int n4) {
  int i = blockIdx.x * blockDim.x + threadIdx.x;
  int stride = gridDim.x * blockDim.x;
  for (; i < n4; i += stride) {
    float4 v = reinterpret_cast<const float4*>(src)[i];
    u32 lo = (u32)f2bf(v.x) | ((u32)f2bf(v.y) << 16);
    u32 hi = (u32)f2bf(v.z) | ((u32)f2bf(v.w) << 16);
    reinterpret_cast<uint2*>(dst)[i] = make_uint2(lo, hi);
  }
}

// ---------------- router: logits + softmax + top8 + reroute (+ x->bf16) ----------------
__global__ void router_kernel(const float* __restrict__ x, const float* __restrict__ gw,
                              const float* __restrict__ sim,
                              int* __restrict__ slot_e, float* __restrict__ slot_w,
                              u16* __restrict__ xb) {
  int t = blockIdx.x;
  __shared__ float xs[HID];
  __shared__ float logits[NE];
  const float* xr = x + (size_t)t * HID;
  for (int i = threadIdx.x; i < HID / 4; i += 256)
    reinterpret_cast<float4*>(xs)[i] = reinterpret_cast<const float4*>(xr)[i];
  __syncthreads();
  {
    int i = threadIdx.x;  // HID/8 == 256
    float4 v0 = reinterpret_cast<float4*>(xs)[i * 2];
    float4 v1 = reinterpret_cast<float4*>(xs)[i * 2 + 1];
    uint4 o;
    o.x = (u32)f2bf(v0.x) | ((u32)f2bf(v0.y) << 16);
    o.y = (u32)f2bf(v0.z) | ((u32)f2bf(v0.w) << 16);
    o.z = (u32)f2bf(v1.x) | ((u32)f2bf(v1.y) << 16);
    o.w = (u32)f2bf(v1.z) | ((u32)f2bf(v1.w) << 16);
    reinterpret_cast<uint4*>(xb + (size_t)t * HID)[i] = o;
  }
  int e = threadIdx.x >> 3, part = threadIdx.x & 7;
  const float4* wv = reinterpret_cast<const float4*>(gw + (size_t)e * HID + part * 256);
  const float4* xv = reinterpret_cast<const float4*>(xs + part * 256);
  float s = 0.f;
#pragma unroll
  for (int j = 0; j < 64; ++j) {
    float4 a = xv[j], b = wv[j];
    s += a.x * b.x + a.y * b.y + a.z * b.z + a.w * b.w;
  }
  s += __shfl_xor(s, 1); s += __shfl_xor(s, 2); s += __shfl_xor(s, 4);
  if (part == 0) logits[e] = s;
  __syncthreads();
  if (threadIdx.x == 0) {
    float l[NE];
#pragma unroll
    for (int i = 0; i < NE; ++i) l[i] = logits[i];
    unsigned mask = 0;
    int idx[8]; float lv[8];
#pragma unroll
    for (int k = 0; k < 8; ++k) {
      float best = -3.4e38f; int bi = 0;
#pragma unroll
      for (int i = 0; i < NE; ++i) {
        bool ok = (((mask >> i) & 1u) == 0u) && (l[i] > best);
        best = ok ? l[i] : best;
        bi = ok ? i : bi;
      }
      idx[k] = bi; lv[k] = best; mask |= (1u << bi);
    }
    float w[8]; float ssum = 0.f;
#pragma unroll
    for (int k = 0; k < 8; ++k) { w[k] = __expf(lv[k] - lv[0]); ssum += w[k]; }
    float inv = 1.f / ssum;
    int base = t * 8;
#pragma unroll
    for (int i = 0; i < 4; ++i) { slot_e[base + i] = idx[i]; slot_w[base + i] = w[i] * inv; }
#pragma unroll
    for (int j = 0; j < 4; ++j) {
      int sj = idx[4 + j];
      float best = -2.f; int bsel = idx[0];
#pragma unroll
      for (int i = 0; i < 4; ++i) {
        int pe = idx[i];
        float sv = sim[sj * NE + pe];
        bool ok = sv > best;
        best = ok ? sv : best;
        bsel = ok ? pe : bsel;
      }
      int ns = (best < 0.5f) ? sj : bsel;
      slot_e[base + 4 + j] = ns; slot_w[base + 4 + j] = w[4 + j] * inv;
    }
  }
}

// ---------------- counting sort: hist / scan / place ----------------
__global__ void hist_kernel(const int* __restrict__ slot_e, int* __restrict__ blockCounts) {
  __shared__ int cnt[NE];
  if (threadIdx.x < NE) cnt[threadIdx.x] = 0;
  __syncthreads();
  int i = blockIdx.x * 256 + threadIdx.x;
  atomicAdd(&cnt[slot_e[i]], 1);
  __syncthreads();
  if (threadIdx.x < NE) blockCounts[threadIdx.x * NB + blockIdx.x] = cnt[threadIdx.x];
}

__global__ void scan_kernel(const int* __restrict__ blockCounts, int* __restrict__ startEB,
                            int* __restrict__ tile_e, int* __restrict__ tile_row0,
                            int* __restrict__ tile_cnt, int* __restrict__ tileCount) {
  __shared__ int totals[NE];
  __shared__ int bases[NE];
  int t = threadIdx.x;
  if (t < NE) {
    int run = 0;
    for (int b = 0; b < NB; ++b) run += blockCounts[t * NB + b];
    totals[t] = run;
  }
  __syncthreads();
  if (t == 0) {
    int base = 0, nt = 0;
    for (int e = 0; e < NE; ++e) {
      bases[e] = base;
      int tot = totals[e];
      for (int i = 0; i < tot; i += MT) {
        tile_e[nt] = e;
        tile_row0[nt] = base + i;
        tile_cnt[nt] = (tot - i < MT) ? (tot - i) : MT;
        ++nt;
      }
      base += tot;
    }
    *tileCount = nt;
  }
  __syncthreads();
  if (t < NE) {
    int run = bases[t];
    for (int b = 0; b < NB; ++b) {
      startEB[t * NB + b] = run;
      run += blockCounts[t * NB + b];
    }
  }
}

__global__ void place_kernel(const int* __restrict__ slot_e, const float* __restrict__ slot_w,
                             const int* __restrict__ startEB,
                             int* __restrict__ perm_token, float* __restrict__ perm_w,
                             int* __restrict__ inv) {
  __shared__ int se[256];
  __shared__ float sw[256];
  int b = blockIdx.x;
  for (int i = threadIdx.x; i < 256; i += 64) {
    se[i] = slot_e[b * 256 + i];
    sw[i] = slot_w[b * 256 + i];
  }
  __syncthreads();
  int e = threadIdx.x;
  if (e < NE) {
    int pos = startEB[e * NB + b];
    for (int i = 0; i < 256; ++i) {
      if (se[i] == e) {
        perm_token[pos] = (b * 256 + i) >> 3;
        perm_w[pos] = sw[i];
        inv[b * 256 + i] = pos;
        ++pos;
      }
    }
  }
}

// ---------------- gate_up GEMM: counted-vmcnt pipeline ----------------
__global__ __launch_bounds__(256) void gu_fast(
    const u16* __restrict__ xb, const u16* __restrict__ wgub,
    const int* __restrict__ perm_token,
    const int* __restrict__ tile_e, const int* __restrict__ tile_row0,
    const int* __restrict__ tile_cnt, const int* __restrict__ tileCount,
    u16* __restrict__ h_perm) {
  int tile = blockIdx.y;
  if (tile >= *tileCount) return;
  int e = tile_e[tile], row0 = tile_row0[tile], cnt = tile_cnt[tile];
  int n0 = blockIdx.x * 64;
  __shared__ __align__(16) u16 As[2][MT * 64];   // XOR-swizzled via source
  __shared__ __align__(16) u16 Bs[2][MT * 64];   // rows 0-63 gate, 64-127 up
  __shared__ int toks[MT];
  if (threadIdx.x < MT) {
    int idx = row0 + (int)threadIdx.x;
    if (idx > NSLOT - 1) idx = NSLOT - 1;
    toks[threadIdx.x] = perm_token[idx];
  }
  int wave = threadIdx.x >> 6, lane = threadIdx.x & 63;
  int wr = wave >> 1, wc = wave & 1;
  int lr = lane & 15, lk = lane >> 4;
  f32x4 zero = {0.f, 0.f, 0.f, 0.f};
  f32x4 accg[4][2], accu[4][2];
#pragma unroll
  for (int m = 0; m < 4; ++m)
#pragma unroll
    for (int n = 0; n < 2; ++n) { accg[m][n] = zero; accu[m][n] = zero; }

  const u16* wgb = wgub + (size_t)e * (2 * DFF) * HID;
  int r_ = (wave * 64 + lane) >> 3;          // base LDS row for issue i=0
  int c_ = lane & 7;

  // 8 gload16 per thread per stage (4 A + 4 B)
  auto stage = [&](int kt, int buf) {
#pragma unroll
    for (int i = 0; i < 4; ++i) {
      int r = r_ + i * 32;
      int j = c_ ^ (r & 7);
      gload16(xb + (size_t)toks[r] * HID + kt + j * 8, (char*)As[buf] + (i * 4 + wave) * 1024);
    }
#pragma unroll
    for (int i = 0; i < 4; ++i) {
      int r = r_ + i * 32;
      int j = c_ ^ (r & 7);
      int wrow = (r < 64) ? (n0 + r) : (DFF + n0 + (r - 64));
      gload16(wgb + (size_t)wrow * HID + kt + j * 8, (char*)Bs[buf] + (i * 4 + wave) * 1024);
    }
  };

  __syncthreads();            // toks ready
  stage(0, 0);
  stage(64, 1);
  int cur = 0;
  const int NK = HID / 64;    // 32
  for (int kti = 0; kti < NK; ++kti) {
    if (kti + 1 < NK) { asm volatile("s_waitcnt vmcnt(8)" ::: "memory"); }
    else              { asm volatile("s_waitcnt vmcnt(0)" ::: "memory"); }
    __builtin_amdgcn_s_barrier();           // buf[cur] fully written, all waves
    char* Ab = (char*)As[cur];
    char* Bb = (char*)Bs[cur];
    __builtin_amdgcn_s_setprio(1);
#pragma unroll
    for (int kf = 0; kf < 2; ++kf) {
      int kb = kf * 64 + lk * 16;
      bf16x8 a[4], bg2[2], bu2[2];
#pragma unroll
      for (int m = 0; m < 4; ++m) {
        int row = wr * 64 + m * 16 + lr;
        a[m] = *reinterpret_cast<bf16x8*>(Ab + ((row * 128 + kb) ^ ((row & 7) << 4)));
      }
#pragma unroll
      for (int n = 0; n < 2; ++n) {
        int rg = wc * 32 + n * 16 + lr;
        int ru = 64 + rg;
        bg2[n] = *reinterpret_cast<bf16x8*>(Bb + ((rg * 128 + kb) ^ ((rg & 7) << 4)));
        bu2[n] = *reinterpret_cast<bf16x8*>(Bb + ((ru * 128 + kb) ^ ((ru & 7) << 4)));
      }
#pragma unroll
      for (int m = 0; m < 4; ++m)
#pragma unroll
        for (int n = 0; n < 2; ++n) {
          accg[m][n] = __builtin_amdgcn_mfma_f32_16x16x32_bf16(a[m], bg2[n], accg[m][n], 0, 0, 0);
          accu[m][n] = __builtin_amdgcn_mfma_f32_16x16x32_bf16(a[m], bu2[n], accu[m][n], 0, 0, 0);
        }
    }
    __builtin_amdgcn_s_setprio(0);
    __builtin_amdgcn_s_barrier();           // all waves done reading buf[cur]
    if (kti + 2 < NK) stage((kti + 2) * 64, cur);  // refill the buffer just consumed
    cur ^= 1;
  }
#pragma unroll
  for (int m = 0; m < 4; ++m)
#pragma unroll
    for (int n = 0; n < 2; ++n)
#pragma unroll
      for (int i = 0; i < 4; ++i) {
        int row = wr * 64 + m * 16 + lk * 4 + i;
        if (row < cnt) {
          int col = n0 + wc * 32 + n * 16 + lr;
          float g = accg[m][n][i], u = accu[m][n][i];
          float h = g / (1.f + __expf(-g)) * u;
          h_perm[(size_t)(row0 + row) * DFF + col] = f2bf(h);
        }
      }
}

// ---------------- down GEMM -> yp (fp16), counted-vmcnt pipeline ----------------
__global__ __launch_bounds__(256) void down_fast(
    const u16* __restrict__ h_perm, const u16* __restrict__ wdb,
    const float* __restrict__ perm_w,
    const int* __restrict__ tile_e, const int* __restrict__ tile_row0,
    const int* __restrict__ tile_cnt, const int* __restrict__ tileCount,
    _Float16* __restrict__ yp) {
  int tile = blockIdx.y;
  if (tile >= *tileCount) return;
  int e = tile_e[tile], row0 = tile_row0[tile], cnt = tile_cnt[tile];
  int n0 = blockIdx.x * 128;
  __shared__ __align__(16) u16 As[2][MT * 64];
  __shared__ __align__(16) u16 Bs[2][MT * 64];
  __shared__ float wts[MT];
  if (threadIdx.x < MT) {
    int idx = row0 + (int)threadIdx.x;
    if (idx > NSLOT - 1) idx = NSLOT - 1;
    wts[threadIdx.x] = perm_w[idx];
  }
  int wave = threadIdx.x >> 6, lane = threadIdx.x & 63;
  int wr = wave >> 1, wc = wave & 1;
  int lr = lane & 15, lk = lane >> 4;
  f32x4 zero = {0.f, 0.f, 0.f, 0.f};
  f32x4 acc[4][4];
#pragma unroll
  for (int m = 0; m < 4; ++m)
#pragma unroll
    for (int n = 0; n < 4; ++n) acc[m][n] = zero;

  const u16* wb = wdb + (size_t)e * HID * DFF;
  int r_ = (wave * 64 + lane) >> 3;
  int c_ = lane & 7;
  int arow0 = row0 + r_;

  auto stage = [&](int kt, int buf) {
#pragma unroll
    for (int i = 0; i < 4; ++i) {
      int r = r_ + i * 32;
      int j = c_ ^ (r & 7);
      int idx = arow0 + i * 32;
      if (idx > NSLOT - 1) idx = NSLOT - 1;
      gload16(h_perm + (size_t)idx * DFF + kt + j * 8, (char*)As[buf] + (i * 4 + wave) * 1024);
    }
#pragma unroll
    for (int i = 0; i < 4; ++i) {
      int r = r_ + i * 32;
      int j = c_ ^ (r & 7);
      gload16(wb + (size_t)(n0 + r) * DFF + kt + j * 8, (char*)Bs[buf] + (i * 4 + wave) * 1024);
    }
  };

  __syncthreads();
  stage(0, 0);
  stage(64, 1);
  int cur = 0;
  const int NK = DFF / 64;    // 12
  for (int kti = 0; kti < NK; ++kti) {
    if (kti + 1 < NK) { asm volatile("s_waitcnt vmcnt(8)" ::: "memory"); }
    else              { asm volatile("s_waitcnt vmcnt(0)" ::: "memory"); }
    __builtin_amdgcn_s_barrier();
    char* Ab = (char*)As[cur];
    char* Bb = (char*)Bs[cur];
    __builtin_amdgcn_s_setprio(1);
#pragma unroll
    for (int kf = 0; kf < 2; ++kf) {
      int kb = kf * 64 + lk * 16;
      bf16x8 a[4], b[4];
#pragma unroll
      for (int m = 0; m < 4; ++m) {
        int row = wr * 64 + m * 16 + lr;
        a[m] = *reinterpret_cast<bf16x8*>(Ab + ((row * 128 + kb) ^ ((row & 7) << 4)));
      }
#pragma unroll
      for (int n = 0; n < 4; ++n) {
        int row = wc * 64 + n * 16 + lr;
        b[n] = *reinterpret_cast<bf16x8*>(Bb + ((row * 128 + kb) ^ ((row & 7) << 4)));
      }
#pragma unroll
      for (int m = 0; m < 4; ++m)
#pragma unroll
        for (int n = 0; n < 4; ++n)
          acc[m][n] = __builtin_amdgcn_mfma_f32_16x16x32_bf16(a[m], b[n], acc[m][n], 0, 0, 0);
    }
    __builtin_amdgcn_s_setprio(0);
    __builtin_amdgcn_s_barrier();
    if (kti + 2 < NK) stage((kti + 2) * 64, cur);
    cur ^= 1;
  }
#pragma unroll
  for (int m = 0; m < 4; ++m)
#pragma unroll
    for (int n = 0; n < 4; ++n)
#pragma unroll
      for (int i = 0; i < 4; ++i) {
        int row = wr * 64 + m * 16 + lk * 4 + i;
        if (row < cnt) {
          int col = n0 + wc * 64 + n * 16 + lr;
          yp[(size_t)(row0 + row) * HID + col] = (_Float16)(acc[m][n][i] * wts[row]);
        }
      }
}

// ---------------- per-token gather-reduce of 8 slots ----------------
__global__ void reduce_kernel(const _Float16* __restrict__ yp, const int* __restrict__ inv,
                              float* __restrict__ y) {
  int t = blockIdx.x;
  __shared__ int pos[8];
  if (threadIdx.x < 8) pos[threadIdx.x] = inv[t * 8 + threadIdx.x];
  __syncthreads();
  int c = threadIdx.x * 8;
  float s[8] = {0.f, 0.f, 0.f, 0.f, 0.f, 0.f, 0.f, 0.f};
#pragma unroll
  for (int j = 0; j < 8; ++j) {
    uint4 v = *reinterpret_cast<const uint4*>(yp + (size_t)pos[j] * HID + c);
    const u16* p = reinterpret_cast<const u16*>(&v);
#pragma unroll
    for (int k = 0; k < 8; ++k) {
      _Float16 h;
      u16 us = p[k];
      __builtin_memcpy(&h, &us, 2);
      s[k] += (float)h;
    }
  }
  float* yo = y + (size_t)t * HID + c;
  float4 o0 = {s[0], s[1], s[2], s[3]};
  float4 o1 = {s[4], s[5], s[6], s[7]};
  *reinterpret_cast<float4*>(yo) = o0;
  *reinterpret_cast<float4*>(yo + 4) = o1;
}

// ================= legacy fallback (ws too small): round-1 style =================
__global__ __launch_bounds__(256, 2) void gu_legacy(
    const u16* __restrict__ xb, const float* __restrict__ wgu,
    const int* __restrict__ perm_token,
    const int* __restrict__ tile_e, const int* __restrict__ tile_row0,
    const int* __restrict__ tile_cnt, const int* __restrict__ tileCount,
    u16* __restrict__ h_perm) {
  int tile = blockIdx.x;
  if (tile >= *tileCount) return;
  int e = tile_e[tile], row0 = tile_row0[tile], cnt = tile_cnt[tile];
  int n0 = blockIdx.y * 64;
  __shared__ __align__(16) u16 As[MT * 64];
  __shared__ __align__(16) u16 Bg[64 * 64];
  __shared__ __align__(16) u16 Bu[64 * 64];
  __shared__ int toks[MT];
  if (threadIdx.x < MT) {
    int idx = row0 + (int)threadIdx.x;
    if (idx > NSLOT - 1) idx = NSLOT - 1;
    toks[threadIdx.x] = perm_token[idx];
  }
  int wave = threadIdx.x >> 6, lane = threadIdx.x & 63;
  int wr = wave >> 1, wc = wave & 1;
  int lr = lane & 15, lk = lane >> 4;
  f32x4 zero = {0.f, 0.f, 0.f, 0.f};
  f32x4 accg[4][2], accu[4][2];
#pragma unroll
  for (int m = 0; m < 4; ++m)
#pragma unroll
    for (int n = 0; n < 2; ++n) { accg[m][n] = zero; accu[m][n] = zero; }
  int achunk = threadIdx.x & 7, arow = threadIdx.x >> 3;
  int bfc = threadIdx.x & 15, brow = threadIdx.x >> 4;
  const float* wbaseg = wgu + (size_t)e * (2 * DFF) * HID + (size_t)n0 * HID;
  const float* wbaseu = wbaseg + (size_t)DFF * HID;
  for (int kt = 0; kt < HID; kt += 64) {
    __syncthreads();
#pragma unroll
    for (int g = 0; g < 4; ++g) {
      int r = g * 32 + arow;
      const u16* src = xb + (size_t)toks[r] * HID + kt + achunk * 8;
      uint4 v = *reinterpret_cast<const uint4*>(src);
      int byte = (r * 128 + achunk * 16) ^ ((r & 7) << 4);
      *reinterpret_cast<uint4*>(reinterpret_cast<char*>(As) + byte) = v;
    }
#pragma unroll
    for (int g = 0; g < 4; ++g) {
      int r = g * 16 + brow;
      float4 vg = *reinterpret_cast<const float4*>(wbaseg + (size_t)r * HID + kt + bfc * 4);
      float4 vu = *reinterpret_cast<const float4*>(wbaseu + (size_t)r * HID + kt + bfc * 4);
      int byte = (r * 128 + bfc * 8) ^ ((r & 7) << 4);
      uint2 pg = make_uint2((u32)f2bf(vg.x) | ((u32)f2bf(vg.y) << 16),
                            (u32)f2bf(vg.z) | ((u32)f2bf(vg.w) << 16));
      uint2 pu = make_uint2((u32)f2bf(vu.x) | ((u32)f2bf(vu.y) << 16),
                            (u32)f2bf(vu.z) | ((u32)f2bf(vu.w) << 16));
      *reinterpret_cast<uint2*>(reinterpret_cast<char*>(Bg) + byte) = pg;
      *reinterpret_cast<uint2*>(reinterpret_cast<char*>(Bu) + byte) = pu;
    }
    __syncthreads();
#pragma unroll
    for (int kf = 0; kf < 2; ++kf) {
      int kb = kf * 64 + lk * 16;
      bf16x8 a[4], bg2[2], bu2[2];
#pragma unroll
      for (int m = 0; m < 4; ++m) {
        int row = wr * 64 + m * 16 + lr;
        a[m] = *reinterpret_cast<bf16x8*>(reinterpret_cast<char*>(As) + ((row * 128 + kb) ^ ((row & 7) << 4)));
      }
#pragma unroll
      for (int n = 0; n < 2; ++n) {
        int row = wc * 32 + n * 16 + lr;
        int byte = (row * 128 + kb) ^ ((row & 7) << 4);
        bg2[n] = *reinterpret_cast<bf16x8*>(reinterpret_cast<char*>(Bg) + byte);
        bu2[n] = *reinterpret_cast<bf16x8*>(reinterpret_cast<char*>(Bu) + byte);
      }
#pragma unroll
      for (int m = 0; m < 4; ++m)
#pragma unroll
        for (int n = 0; n < 2; ++n) {
          accg[m][n] = __builtin_amdgcn_mfma_f32_16x16x32_bf16(a[m], bg2[n], accg[m][n], 0, 0, 0);
          accu[m][n] = __builtin_amdgcn_mfma_f32_16x16x32_bf16(a[m], bu2[n], accu[m][n], 0, 0, 0);
        }
    }
  }
#pragma unroll
  for (int m = 0; m < 4; ++m)
#pragma unroll
    for (int n = 0; n < 2; ++n)
#pragma unroll
      for (int i = 0; i < 4; ++i) {
        int row = wr * 64 + m * 16 + lk * 4 + i;
        if (row < cnt) {
          int col = n0 + wc * 32 + n * 16 + lr;
          float g = accg[m][n][i], u = accu[m][n][i];
          float h = g / (1.f + __expf(-g)) * u;
          h_perm[(size_t)(row0 + row) * DFF + col] = f2bf(h);
        }
      }
}

__global__ __launch_bounds__(256, 2) void down_legacy(
    const u16* __restrict__ h_perm, const float* __restrict__ wd,
    const int* __restrict__ perm_token, const float* __restrict__ perm_w,
    const int* __restrict__ tile_e, const int* __restrict__ tile_row0,
    const int* __restrict__ tile_cnt, const int* __restrict__ tileCount,
    float* __restrict__ y) {
  int tile = blockIdx.x;
  if (tile >= *tileCount) return;
  int e = tile_e[tile], row0 = tile_row0[tile], cnt = tile_cnt[tile];
  int n0 = blockIdx.y * 128;
  __shared__ __align__(16) u16 As[MT * 64];
  __shared__ __align__(16) u16 Bs[MT * 64];
  __shared__ int toks[MT];
  __shared__ float wts[MT];
  if (threadIdx.x < MT) {
    int idx = row0 + (int)threadIdx.x;
    if (idx > NSLOT - 1) idx = NSLOT - 1;
    toks[threadIdx.x] = perm_token[idx];
    wts[threadIdx.x] = perm_w[idx];
  }
  int wave = threadIdx.x >> 6, lane = threadIdx.x & 63;
  int wr = wave >> 1, wc = wave & 1;
  int lr = lane & 15, lk = lane >> 4;
  f32x4 zero = {0.f, 0.f, 0.f, 0.f};
  f32x4 acc[4][4];
#pragma unroll
  for (int m = 0; m < 4; ++m)
#pragma unroll
    for (int n = 0; n < 4; ++n) acc[m][n] = zero;
  int achunk = threadIdx.x & 7, arow = threadIdx.x >> 3;
  int bfc = threadIdx.x & 15, brow = threadIdx.x >> 4;
  const float* wbase = wd + (size_t)e * HID * DFF + (size_t)n0 * DFF;
  for (int kt = 0; kt < DFF; kt += 64) {
    __syncthreads();
#pragma unroll
    for (int g = 0; g < 4; ++g) {
      int r = g * 32 + arow;
      int idx = row0 + r;
      if (idx > NSLOT - 1) idx = NSLOT - 1;
      const u16* src = h_perm + (size_t)idx * DFF + kt + achunk * 8;
      uint4 v = *reinterpret_cast<const uint4*>(src);
      int byte = (r * 128 + achunk * 16) ^ ((r & 7) << 4);
      *reinterpret_cast<uint4*>(reinterpret_cast<char*>(As) + byte) = v;
    }
#pragma unroll
    for (int g = 0; g < 8; ++g) {
      int r = g * 16 + brow;
      float4 v = *reinterpret_cast<const float4*>(wbase + (size_t)r * DFF + kt + bfc * 4);
      int byte = (r * 128 + bfc * 8) ^ ((r & 7) << 4);
      uint2 p = make_uint2((u32)f2bf(v.x) | ((u32)f2bf(v.y) << 16),
                           (u32)f2bf(v.z) | ((u32)f2bf(v.w) << 16));
      *reinterpret_cast<uint2*>(reinterpret_cast<char*>(Bs) + byte) = p;
    }
    __syncthreads();
#pragma unroll
    for (int kf = 0; kf < 2; ++kf) {
      int kb = kf * 64 + lk * 16;
      bf16x8 a[4], b[4];
#pragma unroll
      for (int m = 0; m < 4; ++m) {
        int row = wr * 64 + m * 16 + lr;
        a[m] = *reinterpret_cast<bf16x8*>(reinterpret_cast<char*>(As) + ((row * 128 + kb) ^ ((row & 7) << 4)));
      }
#pragma unroll
      for (int n = 0; n < 4; ++n) {
        int row = wc * 64 + n * 16 + lr;
        b[n] = *reinterpret_cast<bf16x8*>(reinterpret_cast<char*>(Bs) + ((row * 128 + kb) ^ ((row & 7) << 4)));
      }
#pragma unroll
      for (int m = 0; m < 4; ++m)
#pragma unroll
        for (int n = 0; n < 4; ++n)
          acc[m][n] = __builtin_amdgcn_mfma_f32_16x16x32_bf16(a[m], b[n], acc[m][n], 0, 0, 0);
    }
  }
#pragma unroll
  for (int m = 0; m < 4; ++m)
#pragma unroll
    for (int n = 0; n < 4; ++n)
#pragma unroll
      for (int i = 0; i < 4; ++i) {
        int row = wr * 64 + m * 16 + lk * 4 + i;
        if (row < cnt) {
          int col = n0 + wc * 64 + n * 16 + lr;
          float v = acc[m][n][i] * wts[row];
          atomicAdd(&y[(size_t)toks[row] * HID + col], v);
        }
      }
}

extern "C" void kernel_launch(void* const* d_in, const int* in_sizes, int n_in,
                              void* d_out, int out_size, void* d_ws, size_t ws_size,
                              hipStream_t stream) {
  const float* x = (const float*)d_in[0];
  const float* gw = (const float*)d_in[1];
  const float* wgu = (const float*)d_in[2];
  const float* wd = (const float*)d_in[3];
  const float* sim = (const float*)d_in[4];
  float* y = (float*)d_out;

  char* ws = (char*)d_ws;
  size_t off = 0;
  auto alloc = [&](size_t bytes) {
    char* p = ws + off;
    off += (bytes + 255) & ~(size_t)255;
    return p;
  };
  u16* xb = (u16*)alloc((size_t)NTOK * HID * 2);
  u16* h_perm = (u16*)alloc((size_t)NSLOT * DFF * 2);
  int* slot_e = (int*)alloc(NSLOT * 4);
  float* slot_w = (float*)alloc(NSLOT * 4);
  int* perm_token = (int*)alloc(NSLOT * 4);
  float* perm_w = (float*)alloc(NSLOT * 4);
  int* inv = (int*)alloc(NSLOT * 4);
  int* blockCounts = (int*)alloc(NE * NB * 4);
  int* startEB = (int*)alloc(NE * NB * 4);
  int* tile_e = (int*)alloc(MAX_TILES * 4);
  int* tile_row0 = (int*)alloc(MAX_TILES * 4);
  int* tile_cnt = (int*)alloc(MAX_TILES * 4);
  int* tileCount = (int*)alloc(4);
  size_t off_common = off;
  if (off_common > ws_size) return;

  // full-path extras: bf16 weights + fp16 per-slot down output (aliased over wgu_b)
  size_t wgu_elems = (size_t)NE * 2 * DFF * HID;
  size_t wd_elems = (size_t)NE * HID * DFF;
  size_t region_bytes = (size_t)NSLOT * HID * 2;  // yp (268MB) > wgu_b (201MB)
  u16* wd_b = (u16*)alloc(wd_elems * 2);
  char* region = alloc(region_bytes);
  u16* wgu_b = (u16*)region;
  _Float16* yp = (_Float16*)region;
  bool full = (off <= ws_size);

  // common: router (+x->bf16) + sort
  router_kernel<<<NTOK, 256, 0, stream>>>(x, gw, sim, slot_e, slot_w, xb);
  hist_kernel<<<NB, 256, 0, stream>>>(slot_e, blockCounts);
  scan_kernel<<<1, 64, 0, stream>>>(blockCounts, startEB, tile_e, tile_row0, tile_cnt, tileCount);
  place_kernel<<<NB, 64, 0, stream>>>(slot_e, slot_w, startEB, perm_token, perm_w, inv);

  if (full) {
    convertf2b_kernel<<<4096, 256, 0, stream>>>(wgu, wgu_b, (int)(wgu_elems / 4));
    convertf2b_kernel<<<4096, 256, 0, stream>>>(wd, wd_b, (int)(wd_elems / 4));
    gu_fast<<<dim3(DFF / 64, MAX_TILES), 256, 0, stream>>>(
        xb, wgu_b, perm_token, tile_e, tile_row0, tile_cnt, tileCount, h_perm);
    down_fast<<<dim3(HID / 128, MAX_TILES), 256, 0, stream>>>(
        h_perm, wd_b, perm_w, tile_e, tile_row0, tile_cnt, tileCount, yp);
    reduce_kernel<<<NTOK, 256, 0, stream>>>(yp, inv, y);
  } else {
    hipMemsetAsync(d_out, 0, (size_t)NTOK * HID * sizeof(float), stream);
    gu_legacy<<<dim3(MAX_TILES, DFF / 64), 256, 0, stream>>>(
        xb, wgu, perm_token, tile_e, tile_row0, tile_cnt, tileCount, h_perm);
    down_legacy<<<dim3(MAX_TILES, HID / 128), 256, 0, stream>>>(
        h_perm, wd, perm_token, perm_w, tile_e, tile_row0, tile_cnt, tileCount, y);
  }
}

// Round 5
// 1260.471 us; speedup vs baseline: 1.6392x; 1.1533x over previous
//
#include <hip/hip_runtime.h>
#include <stdint.h>
#include <string.h>

#define NTOK 8192
#define HID 2048
#define NE 32
#define DFF 768
#define NSLOT 65536
#define NB 256
#define MT 256
#define MAX_TILES 288   // 65536/256 + 32

typedef unsigned short u16;
typedef unsigned int u32;

using f32x4 = __attribute__((ext_vector_type(4))) float;
using bf16x8 = __attribute__((ext_vector_type(8))) short;

static __device__ __forceinline__ u16 f2bf(float f) {
  u32 x = __float_as_uint(f);
  x += 0x7fffu + ((x >> 16) & 1u);
  return (u16)(x >> 16);
}

typedef const __attribute__((address_space(1))) unsigned int* gp_t;
typedef __attribute__((address_space(3))) unsigned int* lp_t;
static __device__ __forceinline__ void gload16(const void* g, void* l) {
  __builtin_amdgcn_global_load_lds((gp_t)g, (lp_t)l, 16, 0, 0);
}

// ---------------- fp32 -> bf16 convert (weights) ----------------
__global__ void convertf2b_kernel(const float* __restrict__ src, u16* __restrict__ dst, int n4) {
  int i = blockIdx.x * blockDim.x + threadIdx.x;
  int stride = gridDim.x * blockDim.x;
  for (; i < n4; i += stride) {
    float4 v = reinterpret_cast<const float4*>(src)[i];
    u32 lo = (u32)f2bf(v.x) | ((u32)f2bf(v.y) << 16);
    u32 hi = (u32)f2bf(v.z) | ((u32)f2bf(v.w) << 16);
    reinterpret_cast<uint2*>(dst)[i] = make_uint2(lo, hi);
  }
}

// ---------------- router: logits + softmax + top8 + reroute (+ x->bf16) ----------------
__global__ void router_kernel(const float* __restrict__ x, const float* __restrict__ gw,
                              const float* __restrict__ sim,
                              int* __restrict__ slot_e, float* __restrict__ slot_w,
                              u16* __restrict__ xb) {
  int t = blockIdx.x;
  __shared__ float xs[HID];
  __shared__ float logits[NE];
  const float* xr = x + (size_t)t * HID;
  for (int i = threadIdx.x; i < HID / 4; i += 256)
    reinterpret_cast<float4*>(xs)[i] = reinterpret_cast<const float4*>(xr)[i];
  __syncthreads();
  {
    int i = threadIdx.x;  // HID/8 == 256
    float4 v0 = reinterpret_cast<float4*>(xs)[i * 2];
    float4 v1 = reinterpret_cast<float4*>(xs)[i * 2 + 1];
    uint4 o;
    o.x = (u32)f2bf(v0.x) | ((u32)f2bf(v0.y) << 16);
    o.y = (u32)f2bf(v0.z) | ((u32)f2bf(v0.w) << 16);
    o.z = (u32)f2bf(v1.x) | ((u32)f2bf(v1.y) << 16);
    o.w = (u32)f2bf(v1.z) | ((u32)f2bf(v1.w) << 16);
    reinterpret_cast<uint4*>(xb + (size_t)t * HID)[i] = o;
  }
  int e = threadIdx.x >> 3, part = threadIdx.x & 7;
  const float4* wv = reinterpret_cast<const float4*>(gw + (size_t)e * HID + part * 256);
  const float4* xv = reinterpret_cast<const float4*>(xs + part * 256);
  float s = 0.f;
#pragma unroll
  for (int j = 0; j < 64; ++j) {
    float4 a = xv[j], b = wv[j];
    s += a.x * b.x + a.y * b.y + a.z * b.z + a.w * b.w;
  }
  s += __shfl_xor(s, 1); s += __shfl_xor(s, 2); s += __shfl_xor(s, 4);
  if (part == 0) logits[e] = s;
  __syncthreads();
  if (threadIdx.x == 0) {
    float l[NE];
#pragma unroll
    for (int i = 0; i < NE; ++i) l[i] = logits[i];
    unsigned mask = 0;
    int idx[8]; float lv[8];
#pragma unroll
    for (int k = 0; k < 8; ++k) {
      float best = -3.4e38f; int bi = 0;
#pragma unroll
      for (int i = 0; i < NE; ++i) {
        bool ok = (((mask >> i) & 1u) == 0u) && (l[i] > best);
        best = ok ? l[i] : best;
        bi = ok ? i : bi;
      }
      idx[k] = bi; lv[k] = best; mask |= (1u << bi);
    }
    float w[8]; float ssum = 0.f;
#pragma unroll
    for (int k = 0; k < 8; ++k) { w[k] = __expf(lv[k] - lv[0]); ssum += w[k]; }
    float inv = 1.f / ssum;
    int base = t * 8;
#pragma unroll
    for (int i = 0; i < 4; ++i) { slot_e[base + i] = idx[i]; slot_w[base + i] = w[i] * inv; }
#pragma unroll
    for (int j = 0; j < 4; ++j) {
      int sj = idx[4 + j];
      float best = -2.f; int bsel = idx[0];
#pragma unroll
      for (int i = 0; i < 4; ++i) {
        int pe = idx[i];
        float sv = sim[sj * NE + pe];
        bool ok = sv > best;
        best = ok ? sv : best;
        bsel = ok ? pe : bsel;
      }
      int ns = (best < 0.5f) ? sj : bsel;
      slot_e[base + 4 + j] = ns; slot_w[base + 4 + j] = w[4 + j] * inv;
    }
  }
}

// ---------------- counting sort: hist / scan / place ----------------
__global__ void hist_kernel(const int* __restrict__ slot_e, int* __restrict__ blockCounts) {
  __shared__ int cnt[NE];
  if (threadIdx.x < NE) cnt[threadIdx.x] = 0;
  __syncthreads();
  int i = blockIdx.x * 256 + threadIdx.x;
  atomicAdd(&cnt[slot_e[i]], 1);
  __syncthreads();
  if (threadIdx.x < NE) blockCounts[threadIdx.x * NB + blockIdx.x] = cnt[threadIdx.x];
}

__global__ void scan_kernel(const int* __restrict__ blockCounts, int* __restrict__ startEB,
                            int* __restrict__ tile_e, int* __restrict__ tile_row0,
                            int* __restrict__ tile_cnt, int* __restrict__ tileCount) {
  __shared__ int totals[NE];
  __shared__ int bases[NE];
  int t = threadIdx.x;
  if (t < NE) {
    int run = 0;
    for (int b = 0; b < NB; ++b) run += blockCounts[t * NB + b];
    totals[t] = run;
  }
  __syncthreads();
  if (t == 0) {
    int base = 0, nt = 0;
    for (int e = 0; e < NE; ++e) {
      bases[e] = base;
      int tot = totals[e];
      for (int i = 0; i < tot; i += MT) {
        tile_e[nt] = e;
        tile_row0[nt] = base + i;
        tile_cnt[nt] = (tot - i < MT) ? (tot - i) : MT;
        ++nt;
      }
      base += tot;
    }
    *tileCount = nt;
  }
  __syncthreads();
  if (t < NE) {
    int run = bases[t];
    for (int b = 0; b < NB; ++b) {
      startEB[t * NB + b] = run;
      run += blockCounts[t * NB + b];
    }
  }
}

__global__ void place_kernel(const int* __restrict__ slot_e, const float* __restrict__ slot_w,
                             const int* __restrict__ startEB,
                             int* __restrict__ perm_token, float* __restrict__ perm_w,
                             int* __restrict__ inv) {
  __shared__ int se[256];
  __shared__ float sw[256];
  int b = blockIdx.x;
  for (int i = threadIdx.x; i < 256; i += 64) {
    se[i] = slot_e[b * 256 + i];
    sw[i] = slot_w[b * 256 + i];
  }
  __syncthreads();
  int e = threadIdx.x;
  if (e < NE) {
    int pos = startEB[e * NB + b];
    for (int i = 0; i < 256; ++i) {
      if (se[i] == e) {
        perm_token[pos] = (b * 256 + i) >> 3;
        perm_w[pos] = sw[i];
        inv[b * 256 + i] = pos;
        ++pos;
      }
    }
  }
}

// ---------------- 8-phase 256x256 grouped GEMM machinery ----------------
// Per phase: 16 MFMA (one m-half x 4 n x one kk). Regions: [buf][kk] for A,B.
// Ring staging (1 half-matrix = 2 gload16/thread per phase), vmcnt(8) at even phases.

#define GUMM(AR, M_)                                                                   \
  acc[M_][0] = __builtin_amdgcn_mfma_f32_16x16x32_bf16(AR, b0, acc[M_][0], 0, 0, 0);   \
  acc[M_][1] = __builtin_amdgcn_mfma_f32_16x16x32_bf16(AR, b1, acc[M_][1], 0, 0, 0);   \
  acc[M_][2] = __builtin_amdgcn_mfma_f32_16x16x32_bf16(AR, b2, acc[M_][2], 0, 0, 0);   \
  acc[M_][3] = __builtin_amdgcn_mfma_f32_16x16x32_bf16(AR, b3, acc[M_][3], 0, 0, 0);

#define PH8(BUF, KK, MH, WAITK, ...)                                                   \
  do {                                                                                 \
    const u16* Ap_ = &SA[BUF][KK][abase + (MH) * 2048];                                \
    const u16* Bp_ = &SB[BUF][KK][0];                                                  \
    bf16x8 a0_ = *(const bf16x8*)(Ap_);                                                \
    bf16x8 a1_ = *(const bf16x8*)(Ap_ + 512);                                          \
    bf16x8 a2_ = *(const bf16x8*)(Ap_ + 1024);                                         \
    bf16x8 a3_ = *(const bf16x8*)(Ap_ + 1536);                                         \
    if (!(MH)) {                                                                       \
      b0 = *(const bf16x8*)(Bp_ + boff0);                                              \
      b1 = *(const bf16x8*)(Bp_ + boff1);                                              \
      b2 = *(const bf16x8*)(Bp_ + boff2);                                              \
      b3 = *(const bf16x8*)(Bp_ + boff3);                                              \
    }                                                                                  \
    __VA_ARGS__;                                                                       \
    if (WAITK) {                                                                       \
      if (tail) { asm volatile("s_waitcnt vmcnt(0)" ::: "memory"); }                   \
      else      { asm volatile("s_waitcnt vmcnt(8)" ::: "memory"); }                   \
    }                                                                                  \
    __builtin_amdgcn_s_barrier();                                                      \
    asm volatile("s_waitcnt lgkmcnt(0)" ::: "memory");                                 \
    __builtin_amdgcn_sched_barrier(0);                                                 \
    __builtin_amdgcn_s_setprio(1);                                                     \
    GUMM(a0_, (MH) * 4 + 0)                                                            \
    GUMM(a1_, (MH) * 4 + 1)                                                            \
    GUMM(a2_, (MH) * 4 + 2)                                                            \
    GUMM(a3_, (MH) * 4 + 3)                                                            \
    __builtin_amdgcn_s_setprio(0);                                                     \
    __builtin_amdgcn_s_barrier();                                                      \
  } while (0)

// ---------------- gate_up GEMM: 256 slots x (128 gate + 128 up cols) ----------------
__global__ __launch_bounds__(512, 2) void gu_fast(
    const u16* __restrict__ xb, const u16* __restrict__ wgub,
    const int* __restrict__ perm_token,
    const int* __restrict__ tile_e, const int* __restrict__ tile_row0,
    const int* __restrict__ tile_cnt, const int* __restrict__ tileCount,
    u16* __restrict__ h_perm) {
  int tile = blockIdx.y;
  if (tile >= *tileCount) return;
  int e = tile_e[tile], row0 = tile_row0[tile], cnt = tile_cnt[tile];
  int n0g = blockIdx.x * 128;
  __shared__ __align__(16) u16 SA[2][2][8192];   // [buf][kk][256 rows x 32 K]
  __shared__ __align__(16) u16 SB[2][2][8192];   // rows 0-127 gate, 128-255 up
  __shared__ int toks[256];
  int tid = threadIdx.x;
  if (tid < 256) {
    int idx = row0 + tid;
    if (idx > NSLOT - 1) idx = NSLOT - 1;
    toks[tid] = perm_token[idx];
  }
  __syncthreads();
  int wave = tid >> 6, lane = tid & 63;
  int wr = wave >> 2, wc = wave & 3;
  int lr = lane & 15, lk = lane >> 4;
  // stage constants: each thread loads 2x16B per half-matrix stage
  int sr0 = tid >> 2;                       // rows 0..127 (+128 for 2nd load)
  int sc0 = (tid & 3) ^ ((tid >> 3) & 3);   // pre-swizzled K-chunk
  const u16* gA0 = xb + (size_t)toks[sr0] * HID + sc0 * 8;
  const u16* gA1 = xb + (size_t)toks[128 + sr0] * HID + sc0 * 8;
  const u16* wgb = wgub + (size_t)e * (2 * DFF) * HID;
  const u16* gB0 = wgb + (size_t)(n0g + sr0) * HID + sc0 * 8;          // gate row
  const u16* gB1 = wgb + (size_t)(DFF + n0g + sr0) * HID + sc0 * 8;    // up row
  int d0 = tid * 8, d1 = 4096 + tid * 8;    // linear LDS dests (u16 units)

  // frag read offsets (u16 units), swizzle slot = lk ^ ((lr>>1)&3)
  int slot8 = (lk ^ ((lr >> 1) & 3)) * 8;
  int abase = (wr * 128 + lr) * 32 + slot8;
  int boff0 = (wc * 32 + 0 * 16 + lr) * 32 + slot8;          // gate
  int boff1 = (wc * 32 + 1 * 16 + lr) * 32 + slot8;          // gate
  int boff2 = (128 + wc * 32 + 0 * 16 + lr) * 32 + slot8;    // up
  int boff3 = (128 + wc * 32 + 1 * 16 + lr) * 32 + slot8;    // up

  f32x4 acc[8][4];
  f32x4 zero = {0.f, 0.f, 0.f, 0.f};
#pragma unroll
  for (int m = 0; m < 8; ++m)
#pragma unroll
    for (int n = 0; n < 4; ++n) acc[m][n] = zero;
  bf16x8 b0, b1, b2, b3;

#define GU_SGA(BUF, KK, KT) do { \
    gload16(gA0 + (KT) + (KK) * 32, &SA[BUF][KK][d0]); \
    gload16(gA1 + (KT) + (KK) * 32, &SA[BUF][KK][d1]); } while (0)
#define GU_SGB(BUF, KK, KT) do { \
    gload16(gB0 + (KT) + (KK) * 32, &SB[BUF][KK][d0]); \
    gload16(gB1 + (KT) + (KK) * 32, &SB[BUF][KK][d1]); } while (0)

  // prologue: t0 full (buf0), t1.kk0 (buf1) = 6 half-stages (12 loads)
  GU_SGA(0, 0, 0); GU_SGB(0, 0, 0);
  GU_SGA(0, 1, 0); GU_SGB(0, 1, 0);
  GU_SGA(1, 0, 64); GU_SGB(1, 0, 64);
  asm volatile("s_waitcnt vmcnt(8)" ::: "memory");
  __builtin_amdgcn_s_barrier();

  const int NKT = HID / 64;   // 32
  const int NI = NKT / 2;     // 16
  for (int it = 0; it < NI; ++it) {
    bool tail = (it + 2 >= NI);
    bool st = (it + 1 < NI);
    int ktA = (2 * it + 1) * 64;
    int ktB = (2 * it + 2) * 64;
    int ktC = (2 * it + 3) * 64;
    PH8(0, 0, 0, 0, GU_SGA(1, 1, ktA));            // ph1: compute t.kk0 mh0
    PH8(0, 0, 1, 1, GU_SGB(1, 1, ktA));            // ph2
    PH8(0, 1, 0, 0, if (st) GU_SGA(0, 0, ktB));    // ph3: t.kk1
    PH8(0, 1, 1, 1, if (st) GU_SGB(0, 0, ktB));    // ph4
    PH8(1, 0, 0, 0, if (st) GU_SGA(0, 1, ktB));    // ph5: t+1.kk0
    PH8(1, 0, 1, 1, if (st) GU_SGB(0, 1, ktB));    // ph6
    PH8(1, 1, 0, 0, if (st) GU_SGA(1, 0, ktC));    // ph7: t+1.kk1
    PH8(1, 1, 1, 1, if (st) GU_SGB(1, 0, ktC));    // ph8
  }

  // epilogue: h = silu(g) * u ; acc[m][0,1]=gate cols, acc[m][2,3]=up cols
#pragma unroll
  for (int m = 0; m < 8; ++m)
#pragma unroll
    for (int i = 0; i < 4; ++i) {
      int row = wr * 128 + m * 16 + lk * 4 + i;
      if (row < cnt) {
#pragma unroll
        for (int nf = 0; nf < 2; ++nf) {
          int col = n0g + wc * 32 + nf * 16 + lr;
          float g = acc[m][nf][i], u = acc[m][nf + 2][i];
          float h = g / (1.f + __expf(-g)) * u;
          h_perm[(size_t)(row0 + row) * DFF + col] = f2bf(h);
        }
      }
    }
#undef GU_SGA
#undef GU_SGB
}

// ---------------- down GEMM: 256 slots x 256 hid cols -> yp (fp16) ----------------
__global__ __launch_bounds__(512, 2) void down_fast(
    const u16* __restrict__ h_perm, const u16* __restrict__ wdb,
    const float* __restrict__ perm_w,
    const int* __restrict__ tile_e, const int* __restrict__ tile_row0,
    const int* __restrict__ tile_cnt, const int* __restrict__ tileCount,
    _Float16* __restrict__ yp) {
  int tile = blockIdx.y;
  if (tile >= *tileCount) return;
  int e = tile_e[tile], row0 = tile_row0[tile], cnt = tile_cnt[tile];
  int n0 = blockIdx.x * 256;
  __shared__ __align__(16) u16 SA[2][2][8192];
  __shared__ __align__(16) u16 SB[2][2][8192];
  __shared__ float wts[256];
  int tid = threadIdx.x;
  if (tid < 256) {
    int idx = row0 + tid;
    if (idx > NSLOT - 1) idx = NSLOT - 1;
    wts[tid] = perm_w[idx];
  }
  __syncthreads();
  int wave = tid >> 6, lane = tid & 63;
  int wr = wave >> 2, wc = wave & 3;
  int lr = lane & 15, lk = lane >> 4;
  int sr0 = tid >> 2;
  int sc0 = (tid & 3) ^ ((tid >> 3) & 3);
  int ia0 = row0 + sr0;       if (ia0 > NSLOT - 1) ia0 = NSLOT - 1;
  int ia1 = row0 + 128 + sr0; if (ia1 > NSLOT - 1) ia1 = NSLOT - 1;
  const u16* gA0 = h_perm + (size_t)ia0 * DFF + sc0 * 8;
  const u16* gA1 = h_perm + (size_t)ia1 * DFF + sc0 * 8;
  const u16* wb = wdb + (size_t)e * HID * DFF;
  const u16* gB0 = wb + (size_t)(n0 + sr0) * DFF + sc0 * 8;
  const u16* gB1 = wb + (size_t)(n0 + 128 + sr0) * DFF + sc0 * 8;
  int d0 = tid * 8, d1 = 4096 + tid * 8;

  int slot8 = (lk ^ ((lr >> 1) & 3)) * 8;
  int abase = (wr * 128 + lr) * 32 + slot8;
  int boff0 = (wc * 64 + 0 * 16 + lr) * 32 + slot8;
  int boff1 = (wc * 64 + 1 * 16 + lr) * 32 + slot8;
  int boff2 = (wc * 64 + 2 * 16 + lr) * 32 + slot8;
  int boff3 = (wc * 64 + 3 * 16 + lr) * 32 + slot8;

  f32x4 acc[8][4];
  f32x4 zero = {0.f, 0.f, 0.f, 0.f};
#pragma unroll
  for (int m = 0; m < 8; ++m)
#pragma unroll
    for (int n = 0; n < 4; ++n) acc[m][n] = zero;
  bf16x8 b0, b1, b2, b3;

#define DN_SGA(BUF, KK, KT) do { \
    gload16(gA0 + (KT) + (KK) * 32, &SA[BUF][KK][d0]); \
    gload16(gA1 + (KT) + (KK) * 32, &SA[BUF][KK][d1]); } while (0)
#define DN_SGB(BUF, KK, KT) do { \
    gload16(gB0 + (KT) + (KK) * 32, &SB[BUF][KK][d0]); \
    gload16(gB1 + (KT) + (KK) * 32, &SB[BUF][KK][d1]); } while (0)

  DN_SGA(0, 0, 0); DN_SGB(0, 0, 0);
  DN_SGA(0, 1, 0); DN_SGB(0, 1, 0);
  DN_SGA(1, 0, 64); DN_SGB(1, 0, 64);
  asm volatile("s_waitcnt vmcnt(8)" ::: "memory");
  __builtin_amdgcn_s_barrier();

  const int NKT = DFF / 64;   // 12
  const int NI = NKT / 2;     // 6
  for (int it = 0; it < NI; ++it) {
    bool tail = (it + 2 >= NI);
    bool st = (it + 1 < NI);
    int ktA = (2 * it + 1) * 64;
    int ktB = (2 * it + 2) * 64;
    int ktC = (2 * it + 3) * 64;
    PH8(0, 0, 0, 0, DN_SGA(1, 1, ktA));
    PH8(0, 0, 1, 1, DN_SGB(1, 1, ktA));
    PH8(0, 1, 0, 0, if (st) DN_SGA(0, 0, ktB));
    PH8(0, 1, 1, 1, if (st) DN_SGB(0, 0, ktB));
    PH8(1, 0, 0, 0, if (st) DN_SGA(0, 1, ktB));
    PH8(1, 0, 1, 1, if (st) DN_SGB(0, 1, ktB));
    PH8(1, 1, 0, 0, if (st) DN_SGA(1, 0, ktC));
    PH8(1, 1, 1, 1, if (st) DN_SGB(1, 0, ktC));
  }

#pragma unroll
  for (int m = 0; m < 8; ++m)
#pragma unroll
    for (int i = 0; i < 4; ++i) {
      int row = wr * 128 + m * 16 + lk * 4 + i;
      if (row < cnt) {
        float wt = wts[row];
#pragma unroll
        for (int nf = 0; nf < 4; ++nf) {
          int col = n0 + wc * 64 + nf * 16 + lr;
          yp[(size_t)(row0 + row) * HID + col] = (_Float16)(acc[m][nf][i] * wt);
        }
      }
    }
#undef DN_SGA
#undef DN_SGB
}

// ---------------- per-token gather-reduce of 8 slots ----------------
__global__ void reduce_kernel(const _Float16* __restrict__ yp, const int* __restrict__ inv,
                              float* __restrict__ y) {
  int t = blockIdx.x;
  __shared__ int pos[8];
  if (threadIdx.x < 8) pos[threadIdx.x] = inv[t * 8 + threadIdx.x];
  __syncthreads();
  int c = threadIdx.x * 8;
  float s[8] = {0.f, 0.f, 0.f, 0.f, 0.f, 0.f, 0.f, 0.f};
#pragma unroll
  for (int j = 0; j < 8; ++j) {
    uint4 v = *reinterpret_cast<const uint4*>(yp + (size_t)pos[j] * HID + c);
    const u16* p = reinterpret_cast<const u16*>(&v);
#pragma unroll
    for (int k = 0; k < 8; ++k) {
      _Float16 h;
      u16 us = p[k];
      __builtin_memcpy(&h, &us, 2);
      s[k] += (float)h;
    }
  }
  float* yo = y + (size_t)t * HID + c;
  float4 o0 = {s[0], s[1], s[2], s[3]};
  float4 o1 = {s[4], s[5], s[6], s[7]};
  *reinterpret_cast<float4*>(yo) = o0;
  *reinterpret_cast<float4*>(yo + 4) = o1;
}

extern "C" void kernel_launch(void* const* d_in, const int* in_sizes, int n_in,
                              void* d_out, int out_size, void* d_ws, size_t ws_size,
                              hipStream_t stream) {
  const float* x = (const float*)d_in[0];
  const float* gw = (const float*)d_in[1];
  const float* wgu = (const float*)d_in[2];
  const float* wd = (const float*)d_in[3];
  const float* sim = (const float*)d_in[4];
  float* y = (float*)d_out;

  char* ws = (char*)d_ws;
  size_t off = 0;
  auto alloc = [&](size_t bytes) {
    char* p = ws + off;
    off += (bytes + 255) & ~(size_t)255;
    return p;
  };
  u16* xb = (u16*)alloc((size_t)NTOK * HID * 2);
  u16* h_perm = (u16*)alloc((size_t)NSLOT * DFF * 2);
  int* slot_e = (int*)alloc(NSLOT * 4);
  float* slot_w = (float*)alloc(NSLOT * 4);
  int* perm_token = (int*)alloc(NSLOT * 4);
  float* perm_w = (float*)alloc(NSLOT * 4);
  int* inv = (int*)alloc(NSLOT * 4);
  int* blockCounts = (int*)alloc(NE * NB * 4);
  int* startEB = (int*)alloc(NE * NB * 4);
  int* tile_e = (int*)alloc(MAX_TILES * 4);
  int* tile_row0 = (int*)alloc(MAX_TILES * 4);
  int* tile_cnt = (int*)alloc(MAX_TILES * 4);
  int* tileCount = (int*)alloc(4);

  // bf16 weights + fp16 per-slot down output (yp aliases wgu_b region)
  size_t wgu_elems = (size_t)NE * 2 * DFF * HID;
  size_t wd_elems = (size_t)NE * HID * DFF;
  size_t region_bytes = (size_t)NSLOT * HID * 2;  // yp (268MB) > wgu_b (201MB)
  u16* wd_b = (u16*)alloc(wd_elems * 2);
  char* region = alloc(region_bytes);
  u16* wgu_b = (u16*)region;
  _Float16* yp = (_Float16*)region;
  if (off > ws_size) return;  // insufficient workspace: fail loudly

  router_kernel<<<NTOK, 256, 0, stream>>>(x, gw, sim, slot_e, slot_w, xb);
  hist_kernel<<<NB, 256, 0, stream>>>(slot_e, blockCounts);
  scan_kernel<<<1, 64, 0, stream>>>(blockCounts, startEB, tile_e, tile_row0, tile_cnt, tileCount);
  place_kernel<<<NB, 64, 0, stream>>>(slot_e, slot_w, startEB, perm_token, perm_w, inv);

  convertf2b_kernel<<<4096, 256, 0, stream>>>(wgu, wgu_b, (int)(wgu_elems / 4));
  convertf2b_kernel<<<4096, 256, 0, stream>>>(wd, wd_b, (int)(wd_elems / 4));
  gu_fast<<<dim3(DFF / 128, MAX_TILES), 512, 0, stream>>>(
      xb, wgu_b, perm_token, tile_e, tile_row0, tile_cnt, tileCount, h_perm);
  down_fast<<<dim3(HID / 256, MAX_TILES), 512, 0, stream>>>(
      h_perm, wd_b, perm_w, tile_e, tile_row0, tile_cnt, tileCount, yp);
  reduce_kernel<<<NTOK, 256, 0, stream>>>(yp, inv, y);
}

// Round 6
// 1221.507 us; speedup vs baseline: 1.6915x; 1.0319x over previous
//
#include <hip/hip_runtime.h>
#include <stdint.h>
#include <string.h>

#define NTOK 8192
#define HID 2048
#define NE 32
#define DFF 768
#define NSLOT 65536
#define NB 256
#define MT 256
#define MAX_TILES 288   // 65536/256 + 32

typedef unsigned short u16;
typedef unsigned int u32;

using f32x4 = __attribute__((ext_vector_type(4))) float;
using bf16x8 = __attribute__((ext_vector_type(8))) short;

static __device__ __forceinline__ u16 f2bf(float f) {
  u32 x = __float_as_uint(f);
  x += 0x7fffu + ((x >> 16) & 1u);
  return (u16)(x >> 16);
}

typedef const __attribute__((address_space(1))) unsigned int* gp_t;
typedef __attribute__((address_space(3))) unsigned int* lp_t;
static __device__ __forceinline__ void gload16(const void* g, void* l) {
  __builtin_amdgcn_global_load_lds((gp_t)g, (lp_t)l, 16, 0, 0);
}

// ---------------- fp32 -> bf16 convert (weights) ----------------
__global__ void convertf2b_kernel(const float* __restrict__ src, u16* __restrict__ dst, int n4) {
  int i = blockIdx.x * blockDim.x + threadIdx.x;
  int stride = gridDim.x * blockDim.x;
  for (; i < n4; i += stride) {
    float4 v = reinterpret_cast<const float4*>(src)[i];
    u32 lo = (u32)f2bf(v.x) | ((u32)f2bf(v.y) << 16);
    u32 hi = (u32)f2bf(v.z) | ((u32)f2bf(v.w) << 16);
    reinterpret_cast<uint2*>(dst)[i] = make_uint2(lo, hi);
  }
}

// ---------------- router: logits + softmax + top8 + reroute (+ x->bf16) ----------------
__global__ void router_kernel(const float* __restrict__ x, const float* __restrict__ gw,
                              const float* __restrict__ sim,
                              int* __restrict__ slot_e, float* __restrict__ slot_w,
                              u16* __restrict__ xb) {
  int t = blockIdx.x;
  __shared__ float xs[HID];
  __shared__ float logits[NE];
  const float* xr = x + (size_t)t * HID;
  for (int i = threadIdx.x; i < HID / 4; i += 256)
    reinterpret_cast<float4*>(xs)[i] = reinterpret_cast<const float4*>(xr)[i];
  __syncthreads();
  {
    int i = threadIdx.x;  // HID/8 == 256
    float4 v0 = reinterpret_cast<float4*>(xs)[i * 2];
    float4 v1 = reinterpret_cast<float4*>(xs)[i * 2 + 1];
    uint4 o;
    o.x = (u32)f2bf(v0.x) | ((u32)f2bf(v0.y) << 16);
    o.y = (u32)f2bf(v0.z) | ((u32)f2bf(v0.w) << 16);
    o.z = (u32)f2bf(v1.x) | ((u32)f2bf(v1.y) << 16);
    o.w = (u32)f2bf(v1.z) | ((u32)f2bf(v1.w) << 16);
    reinterpret_cast<uint4*>(xb + (size_t)t * HID)[i] = o;
  }
  int e = threadIdx.x >> 3, part = threadIdx.x & 7;
  const float4* wv = reinterpret_cast<const float4*>(gw + (size_t)e * HID + part * 256);
  const float4* xv = reinterpret_cast<const float4*>(xs + part * 256);
  float s = 0.f;
#pragma unroll
  for (int j = 0; j < 64; ++j) {
    float4 a = xv[j], b = wv[j];
    s += a.x * b.x + a.y * b.y + a.z * b.z + a.w * b.w;
  }
  s += __shfl_xor(s, 1); s += __shfl_xor(s, 2); s += __shfl_xor(s, 4);
  if (part == 0) logits[e] = s;
  __syncthreads();
  if (threadIdx.x == 0) {
    float l[NE];
#pragma unroll
    for (int i = 0; i < NE; ++i) l[i] = logits[i];
    unsigned mask = 0;
    int idx[8]; float lv[8];
#pragma unroll
    for (int k = 0; k < 8; ++k) {
      float best = -3.4e38f; int bi = 0;
#pragma unroll
      for (int i = 0; i < NE; ++i) {
        bool ok = (((mask >> i) & 1u) == 0u) && (l[i] > best);
        best = ok ? l[i] : best;
        bi = ok ? i : bi;
      }
      idx[k] = bi; lv[k] = best; mask |= (1u << bi);
    }
    float w[8]; float ssum = 0.f;
#pragma unroll
    for (int k = 0; k < 8; ++k) { w[k] = __expf(lv[k] - lv[0]); ssum += w[k]; }
    float inv = 1.f / ssum;
    int base = t * 8;
#pragma unroll
    for (int i = 0; i < 4; ++i) { slot_e[base + i] = idx[i]; slot_w[base + i] = w[i] * inv; }
#pragma unroll
    for (int j = 0; j < 4; ++j) {
      int sj = idx[4 + j];
      float best = -2.f; int bsel = idx[0];
#pragma unroll
      for (int i = 0; i < 4; ++i) {
        int pe = idx[i];
        float sv = sim[sj * NE + pe];
        bool ok = sv > best;
        best = ok ? sv : best;
        bsel = ok ? pe : bsel;
      }
      int ns = (best < 0.5f) ? sj : bsel;
      slot_e[base + 4 + j] = ns; slot_w[base + 4 + j] = w[4 + j] * inv;
    }
  }
}

// ---------------- counting sort: hist / scan / place ----------------
__global__ void hist_kernel(const int* __restrict__ slot_e, int* __restrict__ blockCounts) {
  __shared__ int cnt[NE];
  if (threadIdx.x < NE) cnt[threadIdx.x] = 0;
  __syncthreads();
  int i = blockIdx.x * 256 + threadIdx.x;
  atomicAdd(&cnt[slot_e[i]], 1);
  __syncthreads();
  if (threadIdx.x < NE) blockCounts[threadIdx.x * NB + blockIdx.x] = cnt[threadIdx.x];
}

__global__ void scan_kernel(const int* __restrict__ blockCounts, int* __restrict__ startEB,
                            int* __restrict__ tile_e, int* __restrict__ tile_row0,
                            int* __restrict__ tile_cnt, int* __restrict__ tileCount) {
  __shared__ int totals[NE];
  __shared__ int bases[NE];
  int t = threadIdx.x;
  if (t < NE) {
    int run = 0;
    for (int b = 0; b < NB; ++b) run += blockCounts[t * NB + b];
    totals[t] = run;
  }
  __syncthreads();
  if (t == 0) {
    int base = 0, nt = 0;
    for (int e = 0; e < NE; ++e) {
      bases[e] = base;
      int tot = totals[e];
      for (int i = 0; i < tot; i += MT) {
        tile_e[nt] = e;
        tile_row0[nt] = base + i;
        tile_cnt[nt] = (tot - i < MT) ? (tot - i) : MT;
        ++nt;
      }
      base += tot;
    }
    *tileCount = nt;
  }
  __syncthreads();
  if (t < NE) {
    int run = bases[t];
    for (int b = 0; b < NB; ++b) {
      startEB[t * NB + b] = run;
      run += blockCounts[t * NB + b];
    }
  }
}

__global__ void place_kernel(const int* __restrict__ slot_e, const float* __restrict__ slot_w,
                             const int* __restrict__ startEB,
                             int* __restrict__ perm_token, float* __restrict__ perm_w,
                             int* __restrict__ inv) {
  __shared__ int se[256];
  __shared__ float sw[256];
  int b = blockIdx.x;
  for (int i = threadIdx.x; i < 256; i += 64) {
    se[i] = slot_e[b * 256 + i];
    sw[i] = slot_w[b * 256 + i];
  }
  __syncthreads();
  int e = threadIdx.x;
  if (e < NE) {
    int pos = startEB[e * NB + b];
    for (int i = 0; i < 256; ++i) {
      if (se[i] == e) {
        perm_token[pos] = (b * 256 + i) >> 3;
        perm_w[pos] = sw[i];
        inv[b * 256 + i] = pos;
        ++pos;
      }
    }
  }
}

// ---------------- 8-phase 256x256 grouped GEMM machinery ----------------
// Per phase: 16 MFMA (one m-half x 4 n x one kk). Regions: [buf][kk] for A,B.
// Ring staging, vmcnt(8) at even phases. Compiler-scheduled fine lgkm waits;
// sched_barrier(0) before the closing s_barrier pins waits/MFMA inside the phase.

#define GUMM(AR, M_)                                                                   \
  acc[M_][0] = __builtin_amdgcn_mfma_f32_16x16x32_bf16(AR, b0, acc[M_][0], 0, 0, 0);   \
  acc[M_][1] = __builtin_amdgcn_mfma_f32_16x16x32_bf16(AR, b1, acc[M_][1], 0, 0, 0);   \
  acc[M_][2] = __builtin_amdgcn_mfma_f32_16x16x32_bf16(AR, b2, acc[M_][2], 0, 0, 0);   \
  acc[M_][3] = __builtin_amdgcn_mfma_f32_16x16x32_bf16(AR, b3, acc[M_][3], 0, 0, 0);

#define PH8(BUF, KK, MH, WAITK, ...)                                                   \
  do {                                                                                 \
    const u16* Ap_ = &SA[BUF][KK][abase + (MH) * 2048];                                \
    const u16* Bp_ = &SB[BUF][KK][0];                                                  \
    bf16x8 a0_ = *(const bf16x8*)(Ap_);                                                \
    bf16x8 a1_ = *(const bf16x8*)(Ap_ + 512);                                          \
    bf16x8 a2_ = *(const bf16x8*)(Ap_ + 1024);                                         \
    bf16x8 a3_ = *(const bf16x8*)(Ap_ + 1536);                                         \
    if (!(MH)) {                                                                       \
      b0 = *(const bf16x8*)(Bp_ + boff0);                                              \
      b1 = *(const bf16x8*)(Bp_ + boff1);                                              \
      b2 = *(const bf16x8*)(Bp_ + boff2);                                              \
      b3 = *(const bf16x8*)(Bp_ + boff3);                                              \
    }                                                                                  \
    __VA_ARGS__;                                                                       \
    if (WAITK) {                                                                       \
      if (tail) { asm volatile("s_waitcnt vmcnt(0)" ::: "memory"); }                   \
      else      { asm volatile("s_waitcnt vmcnt(8)" ::: "memory"); }                   \
    }                                                                                  \
    __builtin_amdgcn_s_barrier();                                                      \
    __builtin_amdgcn_s_setprio(1);                                                     \
    GUMM(a0_, (MH) * 4 + 0)                                                            \
    GUMM(a1_, (MH) * 4 + 1)                                                            \
    GUMM(a2_, (MH) * 4 + 2)                                                            \
    GUMM(a3_, (MH) * 4 + 3)                                                            \
    __builtin_amdgcn_s_setprio(0);                                                     \
    __builtin_amdgcn_sched_barrier(0);                                                 \
    __builtin_amdgcn_s_barrier();                                                      \
  } while (0)

// ---------------- gate_up GEMM: 256 slots x (128 gate + 128 up cols) ----------------
__global__ __launch_bounds__(512, 2) void gu_fast(
    const u16* __restrict__ xb, const u16* __restrict__ wgub,
    const int* __restrict__ perm_token,
    const int* __restrict__ tile_e, const int* __restrict__ tile_row0,
    const int* __restrict__ tile_cnt, const int* __restrict__ tileCount,
    u16* __restrict__ h_perm) {
  // XCD clustering: flat%8 = XCD; give each XCD a contiguous 36-tile chunk.
  int flat = blockIdx.x + blockIdx.y * 6;       // NWG = 6*288 = 1728, %8 == 0
  int xcd = flat & 7;
  int j = flat >> 3;                            // 0..215
  int tile = xcd * 36 + j / 6;
  int n0g = (j % 6) * 128;
  if (tile >= *tileCount) return;
  int e = tile_e[tile], row0 = tile_row0[tile], cnt = tile_cnt[tile];
  __shared__ __align__(16) u16 SA[2][2][8192];   // [buf][kk][256 rows x 32 K]
  __shared__ __align__(16) u16 SB[2][2][8192];   // rows 0-127 gate, 128-255 up
  __shared__ int toks[256];
  int tid = threadIdx.x;
  if (tid < 256) {
    int idx = row0 + tid;
    if (idx > NSLOT - 1) idx = NSLOT - 1;
    toks[tid] = perm_token[idx];
  }
  __syncthreads();
  int wave = tid >> 6, lane = tid & 63;
  int wr = wave >> 2, wc = wave & 3;
  int lr = lane & 15, lk = lane >> 4;
  int sr0 = tid >> 2;                       // rows 0..127 (+128 for 2nd load)
  int sc0 = (tid & 3) ^ ((tid >> 3) & 3);   // pre-swizzled K-chunk
  const u16* gA0 = xb + (size_t)toks[sr0] * HID + sc0 * 8;
  const u16* gA1 = xb + (size_t)toks[128 + sr0] * HID + sc0 * 8;
  const u16* wgb = wgub + (size_t)e * (2 * DFF) * HID;
  const u16* gB0 = wgb + (size_t)(n0g + sr0) * HID + sc0 * 8;          // gate row
  const u16* gB1 = wgb + (size_t)(DFF + n0g + sr0) * HID + sc0 * 8;    // up row
  int d0 = tid * 8, d1 = 4096 + tid * 8;    // linear LDS dests (u16 units)

  int slot8 = (lk ^ ((lr >> 1) & 3)) * 8;
  int abase = (wr * 128 + lr) * 32 + slot8;
  int boff0 = (wc * 32 + 0 * 16 + lr) * 32 + slot8;          // gate
  int boff1 = (wc * 32 + 1 * 16 + lr) * 32 + slot8;          // gate
  int boff2 = (128 + wc * 32 + 0 * 16 + lr) * 32 + slot8;    // up
  int boff3 = (128 + wc * 32 + 1 * 16 + lr) * 32 + slot8;    // up

  f32x4 acc[8][4];
  f32x4 zero = {0.f, 0.f, 0.f, 0.f};
#pragma unroll
  for (int m = 0; m < 8; ++m)
#pragma unroll
    for (int n = 0; n < 4; ++n) acc[m][n] = zero;
  bf16x8 b0, b1, b2, b3;

#define GU_SGA(BUF, KK, KT) do { \
    gload16(gA0 + (KT) + (KK) * 32, &SA[BUF][KK][d0]); \
    gload16(gA1 + (KT) + (KK) * 32, &SA[BUF][KK][d1]); } while (0)
#define GU_SGB(BUF, KK, KT) do { \
    gload16(gB0 + (KT) + (KK) * 32, &SB[BUF][KK][d0]); \
    gload16(gB1 + (KT) + (KK) * 32, &SB[BUF][KK][d1]); } while (0)

  // prologue: t0 full (buf0), t1.kk0 (buf1) = 6 half-stages (12 loads)
  GU_SGA(0, 0, 0); GU_SGB(0, 0, 0);
  GU_SGA(0, 1, 0); GU_SGB(0, 1, 0);
  GU_SGA(1, 0, 64); GU_SGB(1, 0, 64);
  asm volatile("s_waitcnt vmcnt(8)" ::: "memory");
  __builtin_amdgcn_s_barrier();

  const int NKT = HID / 64;   // 32
  const int NI = NKT / 2;     // 16
  for (int it = 0; it < NI; ++it) {
    bool tail = (it + 2 >= NI);
    bool st = (it + 1 < NI);
    int ktA = (2 * it + 1) * 64;
    int ktB = (2 * it + 2) * 64;
    int ktC = (2 * it + 3) * 64;
    PH8(0, 0, 0, 0, GU_SGA(1, 1, ktA));            // ph1: compute t.kk0 mh0
    PH8(0, 0, 1, 1, GU_SGB(1, 1, ktA));            // ph2
    PH8(0, 1, 0, 0, if (st) GU_SGA(0, 0, ktB));    // ph3: t.kk1
    PH8(0, 1, 1, 1, if (st) GU_SGB(0, 0, ktB));    // ph4
    PH8(1, 0, 0, 0, if (st) GU_SGA(0, 1, ktB));    // ph5: t+1.kk0
    PH8(1, 0, 1, 1, if (st) GU_SGB(0, 1, ktB));    // ph6
    PH8(1, 1, 0, 0, if (st) GU_SGA(1, 0, ktC));    // ph7: t+1.kk1
    PH8(1, 1, 1, 1, if (st) GU_SGB(1, 0, ktC));    // ph8
  }

  // epilogue: h = silu(g) * u ; acc[m][0,1]=gate cols, acc[m][2,3]=up cols
#pragma unroll
  for (int m = 0; m < 8; ++m)
#pragma unroll
    for (int i = 0; i < 4; ++i) {
      int row = wr * 128 + m * 16 + lk * 4 + i;
      if (row < cnt) {
#pragma unroll
        for (int nf = 0; nf < 2; ++nf) {
          int col = n0g + wc * 32 + nf * 16 + lr;
          float g = acc[m][nf][i], u = acc[m][nf + 2][i];
          float h = g / (1.f + __expf(-g)) * u;
          h_perm[(size_t)(row0 + row) * DFF + col] = f2bf(h);
        }
      }
    }
#undef GU_SGA
#undef GU_SGB
}

// ---------------- down GEMM: 256 slots x 256 hid cols -> yp (fp16) ----------------
__global__ __launch_bounds__(512, 2) void down_fast(
    const u16* __restrict__ h_perm, const u16* __restrict__ wdb,
    const float* __restrict__ perm_w,
    const int* __restrict__ tile_e, const int* __restrict__ tile_row0,
    const int* __restrict__ tile_cnt, const int* __restrict__ tileCount,
    _Float16* __restrict__ yp) {
  int flat = blockIdx.x + blockIdx.y * 8;       // NWG = 8*288 = 2304, %8 == 0
  int xcd = flat & 7;
  int j = flat >> 3;                            // 0..287
  int tile = xcd * 36 + j / 8;
  int n0 = (j % 8) * 256;
  if (tile >= *tileCount) return;
  int e = tile_e[tile], row0 = tile_row0[tile], cnt = tile_cnt[tile];
  __shared__ __align__(16) u16 SA[2][2][8192];
  __shared__ __align__(16) u16 SB[2][2][8192];
  __shared__ float wts[256];
  int tid = threadIdx.x;
  if (tid < 256) {
    int idx = row0 + tid;
    if (idx > NSLOT - 1) idx = NSLOT - 1;
    wts[tid] = perm_w[idx];
  }
  __syncthreads();
  int wave = tid >> 6, lane = tid & 63;
  int wr = wave >> 2, wc = wave & 3;
  int lr = lane & 15, lk = lane >> 4;
  int sr0 = tid >> 2;
  int sc0 = (tid & 3) ^ ((tid >> 3) & 3);
  int ia0 = row0 + sr0;       if (ia0 > NSLOT - 1) ia0 = NSLOT - 1;
  int ia1 = row0 + 128 + sr0; if (ia1 > NSLOT - 1) ia1 = NSLOT - 1;
  const u16* gA0 = h_perm + (size_t)ia0 * DFF + sc0 * 8;
  const u16* gA1 = h_perm + (size_t)ia1 * DFF + sc0 * 8;
  const u16* wb = wdb + (size_t)e * HID * DFF;
  const u16* gB0 = wb + (size_t)(n0 + sr0) * DFF + sc0 * 8;
  const u16* gB1 = wb + (size_t)(n0 + 128 + sr0) * DFF + sc0 * 8;
  int d0 = tid * 8, d1 = 4096 + tid * 8;

  int slot8 = (lk ^ ((lr >> 1) & 3)) * 8;
  int abase = (wr * 128 + lr) * 32 + slot8;
  int boff0 = (wc * 64 + 0 * 16 + lr) * 32 + slot8;
  int boff1 = (wc * 64 + 1 * 16 + lr) * 32 + slot8;
  int boff2 = (wc * 64 + 2 * 16 + lr) * 32 + slot8;
  int boff3 = (wc * 64 + 3 * 16 + lr) * 32 + slot8;

  f32x4 acc[8][4];
  f32x4 zero = {0.f, 0.f, 0.f, 0.f};
#pragma unroll
  for (int m = 0; m < 8; ++m)
#pragma unroll
    for (int n = 0; n < 4; ++n) acc[m][n] = zero;
  bf16x8 b0, b1, b2, b3;

#define DN_SGA(BUF, KK, KT) do { \
    gload16(gA0 + (KT) + (KK) * 32, &SA[BUF][KK][d0]); \
    gload16(gA1 + (KT) + (KK) * 32, &SA[BUF][KK][d1]); } while (0)
#define DN_SGB(BUF, KK, KT) do { \
    gload16(gB0 + (KT) + (KK) * 32, &SB[BUF][KK][d0]); \
    gload16(gB1 + (KT) + (KK) * 32, &SB[BUF][KK][d1]); } while (0)

  DN_SGA(0, 0, 0); DN_SGB(0, 0, 0);
  DN_SGA(0, 1, 0); DN_SGB(0, 1, 0);
  DN_SGA(1, 0, 64); DN_SGB(1, 0, 64);
  asm volatile("s_waitcnt vmcnt(8)" ::: "memory");
  __builtin_amdgcn_s_barrier();

  const int NKT = DFF / 64;   // 12
  const int NI = NKT / 2;     // 6
  for (int it = 0; it < NI; ++it) {
    bool tail = (it + 2 >= NI);
    bool st = (it + 1 < NI);
    int ktA = (2 * it + 1) * 64;
    int ktB = (2 * it + 2) * 64;
    int ktC = (2 * it + 3) * 64;
    PH8(0, 0, 0, 0, DN_SGA(1, 1, ktA));
    PH8(0, 0, 1, 1, DN_SGB(1, 1, ktA));
    PH8(0, 1, 0, 0, if (st) DN_SGA(0, 0, ktB));
    PH8(0, 1, 1, 1, if (st) DN_SGB(0, 0, ktB));
    PH8(1, 0, 0, 0, if (st) DN_SGA(0, 1, ktB));
    PH8(1, 0, 1, 1, if (st) DN_SGB(0, 1, ktB));
    PH8(1, 1, 0, 0, if (st) DN_SGA(1, 0, ktC));
    PH8(1, 1, 1, 1, if (st) DN_SGB(1, 0, ktC));
  }

#pragma unroll
  for (int m = 0; m < 8; ++m)
#pragma unroll
    for (int i = 0; i < 4; ++i) {
      int row = wr * 128 + m * 16 + lk * 4 + i;
      if (row < cnt) {
        float wt = wts[row];
#pragma unroll
        for (int nf = 0; nf < 4; ++nf) {
          int col = n0 + wc * 64 + nf * 16 + lr;
          yp[(size_t)(row0 + row) * HID + col] = (_Float16)(acc[m][nf][i] * wt);
        }
      }
    }
#undef DN_SGA
#undef DN_SGB
}

// ---------------- per-token gather-reduce of 8 slots ----------------
__global__ void reduce_kernel(const _Float16* __restrict__ yp, const int* __restrict__ inv,
                              float* __restrict__ y) {
  int t = blockIdx.x;
  __shared__ int pos[8];
  if (threadIdx.x < 8) pos[threadIdx.x] = inv[t * 8 + threadIdx.x];
  __syncthreads();
  int c = threadIdx.x * 8;
  float s[8] = {0.f, 0.f, 0.f, 0.f, 0.f, 0.f, 0.f, 0.f};
#pragma unroll
  for (int j = 0; j < 8; ++j) {
    uint4 v = *reinterpret_cast<const uint4*>(yp + (size_t)pos[j] * HID + c);
    const u16* p = reinterpret_cast<const u16*>(&v);
#pragma unroll
    for (int k = 0; k < 8; ++k) {
      _Float16 h;
      u16 us = p[k];
      __builtin_memcpy(&h, &us, 2);
      s[k] += (float)h;
    }
  }
  float* yo = y + (size_t)t * HID + c;
  float4 o0 = {s[0], s[1], s[2], s[3]};
  float4 o1 = {s[4], s[5], s[6], s[7]};
  *reinterpret_cast<float4*>(yo) = o0;
  *reinterpret_cast<float4*>(yo + 4) = o1;
}

extern "C" void kernel_launch(void* const* d_in, const int* in_sizes, int n_in,
                              void* d_out, int out_size, void* d_ws, size_t ws_size,
                              hipStream_t stream) {
  const float* x = (const float*)d_in[0];
  const float* gw = (const float*)d_in[1];
  const float* wgu = (const float*)d_in[2];
  const float* wd = (const float*)d_in[3];
  const float* sim = (const float*)d_in[4];
  float* y = (float*)d_out;

  char* ws = (char*)d_ws;
  size_t off = 0;
  auto alloc = [&](size_t bytes) {
    char* p = ws + off;
    off += (bytes + 255) & ~(size_t)255;
    return p;
  };
  u16* xb = (u16*)alloc((size_t)NTOK * HID * 2);
  u16* h_perm = (u16*)alloc((size_t)NSLOT * DFF * 2);
  int* slot_e = (int*)alloc(NSLOT * 4);
  float* slot_w = (float*)alloc(NSLOT * 4);
  int* perm_token = (int*)alloc(NSLOT * 4);
  float* perm_w = (float*)alloc(NSLOT * 4);
  int* inv = (int*)alloc(NSLOT * 4);
  int* blockCounts = (int*)alloc(NE * NB * 4);
  int* startEB = (int*)alloc(NE * NB * 4);
  int* tile_e = (int*)alloc(MAX_TILES * 4);
  int* tile_row0 = (int*)alloc(MAX_TILES * 4);
  int* tile_cnt = (int*)alloc(MAX_TILES * 4);
  int* tileCount = (int*)alloc(4);

  // bf16 weights + fp16 per-slot down output (yp aliases wgu_b region)
  size_t wgu_elems = (size_t)NE * 2 * DFF * HID;
  size_t wd_elems = (size_t)NE * HID * DFF;
  size_t region_bytes = (size_t)NSLOT * HID * 2;  // yp (268MB) > wgu_b (201MB)
  u16* wd_b = (u16*)alloc(wd_elems * 2);
  char* region = alloc(region_bytes);
  u16* wgu_b = (u16*)region;
  _Float16* yp = (_Float16*)region;
  if (off > ws_size) return;  // insufficient workspace: fail loudly

  router_kernel<<<NTOK, 256, 0, stream>>>(x, gw, sim, slot_e, slot_w, xb);
  hist_kernel<<<NB, 256, 0, stream>>>(slot_e, blockCounts);
  scan_kernel<<<1, 64, 0, stream>>>(blockCounts, startEB, tile_e, tile_row0, tile_cnt, tileCount);
  place_kernel<<<NB, 64, 0, stream>>>(slot_e, slot_w, startEB, perm_token, perm_w, inv);

  convertf2b_kernel<<<4096, 256, 0, stream>>>(wgu, wgu_b, (int)(wgu_elems / 4));
  convertf2b_kernel<<<4096, 256, 0, stream>>>(wd, wd_b, (int)(wd_elems / 4));
  gu_fast<<<dim3(DFF / 128, MAX_TILES), 512, 0, stream>>>(
      xb, wgu_b, perm_token, tile_e, tile_row0, tile_cnt, tileCount, h_perm);
  down_fast<<<dim3(HID / 256, MAX_TILES), 512, 0, stream>>>(
      h_perm, wd_b, perm_w, tile_e, tile_row0, tile_cnt, tileCount, yp);
  reduce_kernel<<<NTOK, 256, 0, stream>>>(yp, inv, y);
}

// Round 7
// 1194.035 us; speedup vs baseline: 1.7304x; 1.0230x over previous
//
#include <hip/hip_runtime.h>
#include <stdint.h>
#include <string.h>

#define NTOK 8192
#define HID 2048
#define NE 32
#define DFF 768
#define NSLOT 65536
#define NB 256
#define MT 256
#define MAX_TILES 288   // 65536/256 + 32

typedef unsigned short u16;
typedef unsigned int u32;

using f32x4 = __attribute__((ext_vector_type(4))) float;
using bf16x8 = __attribute__((ext_vector_type(8))) short;

static __device__ __forceinline__ u16 f2bf(float f) {
  u32 x = __float_as_uint(f);
  x += 0x7fffu + ((x >> 16) & 1u);
  return (u16)(x >> 16);
}

typedef const __attribute__((address_space(1))) unsigned int* gp_t;
typedef __attribute__((address_space(3))) unsigned int* lp_t;
static __device__ __forceinline__ void gload16(const void* g, void* l) {
  __builtin_amdgcn_global_load_lds((gp_t)g, (lp_t)l, 16, 0, 0);
}

// ---------------- fp32 -> bf16 convert (weights) ----------------
__global__ void convertf2b_kernel(const float* __restrict__ src, u16* __restrict__ dst, int n4) {
  int i = blockIdx.x * blockDim.x + threadIdx.x;
  int stride = gridDim.x * blockDim.x;
  for (; i < n4; i += stride) {
    float4 v = reinterpret_cast<const float4*>(src)[i];
    u32 lo = (u32)f2bf(v.x) | ((u32)f2bf(v.y) << 16);
    u32 hi = (u32)f2bf(v.z) | ((u32)f2bf(v.w) << 16);
    reinterpret_cast<uint2*>(dst)[i] = make_uint2(lo, hi);
  }
}

// ---------------- router: logits + softmax + top8 + reroute (+ x->bf16) ----------------
__global__ void router_kernel(const float* __restrict__ x, const float* __restrict__ gw,
                              const float* __restrict__ sim,
                              int* __restrict__ slot_e, float* __restrict__ slot_w,
                              u16* __restrict__ xb) {
  int t = blockIdx.x;
  __shared__ float xs[HID];
  __shared__ float logits[NE];
  const float* xr = x + (size_t)t * HID;
  for (int i = threadIdx.x; i < HID / 4; i += 256)
    reinterpret_cast<float4*>(xs)[i] = reinterpret_cast<const float4*>(xr)[i];
  __syncthreads();
  {
    int i = threadIdx.x;  // HID/8 == 256
    float4 v0 = reinterpret_cast<float4*>(xs)[i * 2];
    float4 v1 = reinterpret_cast<float4*>(xs)[i * 2 + 1];
    uint4 o;
    o.x = (u32)f2bf(v0.x) | ((u32)f2bf(v0.y) << 16);
    o.y = (u32)f2bf(v0.z) | ((u32)f2bf(v0.w) << 16);
    o.z = (u32)f2bf(v1.x) | ((u32)f2bf(v1.y) << 16);
    o.w = (u32)f2bf(v1.z) | ((u32)f2bf(v1.w) << 16);
    reinterpret_cast<uint4*>(xb + (size_t)t * HID)[i] = o;
  }
  int e = threadIdx.x >> 3, part = threadIdx.x & 7;
  const float4* wv = reinterpret_cast<const float4*>(gw + (size_t)e * HID + part * 256);
  const float4* xv = reinterpret_cast<const float4*>(xs + part * 256);
  float s = 0.f;
#pragma unroll
  for (int j = 0; j < 64; ++j) {
    float4 a = xv[j], b = wv[j];
    s += a.x * b.x + a.y * b.y + a.z * b.z + a.w * b.w;
  }
  s += __shfl_xor(s, 1); s += __shfl_xor(s, 2); s += __shfl_xor(s, 4);
  if (part == 0) logits[e] = s;
  __syncthreads();
  if (threadIdx.x == 0) {
    float l[NE];
#pragma unroll
    for (int i = 0; i < NE; ++i) l[i] = logits[i];
    unsigned mask = 0;
    int idx[8]; float lv[8];
#pragma unroll
    for (int k = 0; k < 8; ++k) {
      float best = -3.4e38f; int bi = 0;
#pragma unroll
      for (int i = 0; i < NE; ++i) {
        bool ok = (((mask >> i) & 1u) == 0u) && (l[i] > best);
        best = ok ? l[i] : best;
        bi = ok ? i : bi;
      }
      idx[k] = bi; lv[k] = best; mask |= (1u << bi);
    }
    float w[8]; float ssum = 0.f;
#pragma unroll
    for (int k = 0; k < 8; ++k) { w[k] = __expf(lv[k] - lv[0]); ssum += w[k]; }
    float inv = 1.f / ssum;
    int base = t * 8;
#pragma unroll
    for (int i = 0; i < 4; ++i) { slot_e[base + i] = idx[i]; slot_w[base + i] = w[i] * inv; }
#pragma unroll
    for (int j = 0; j < 4; ++j) {
      int sj = idx[4 + j];
      float best = -2.f; int bsel = idx[0];
#pragma unroll
      for (int i = 0; i < 4; ++i) {
        int pe = idx[i];
        float sv = sim[sj * NE + pe];
        bool ok = sv > best;
        best = ok ? sv : best;
        bsel = ok ? pe : bsel;
      }
      int ns = (best < 0.5f) ? sj : bsel;
      slot_e[base + 4 + j] = ns; slot_w[base + 4 + j] = w[4 + j] * inv;
    }
  }
}

// ---------------- counting sort: hist / scan / place ----------------
__global__ void hist_kernel(const int* __restrict__ slot_e, int* __restrict__ blockCounts) {
  __shared__ int cnt[NE];
  if (threadIdx.x < NE) cnt[threadIdx.x] = 0;
  __syncthreads();
  int i = blockIdx.x * 256 + threadIdx.x;
  atomicAdd(&cnt[slot_e[i]], 1);
  __syncthreads();
  if (threadIdx.x < NE) blockCounts[threadIdx.x * NB + blockIdx.x] = cnt[threadIdx.x];
}

__global__ void scan_kernel(const int* __restrict__ blockCounts, int* __restrict__ startEB,
                            int* __restrict__ tile_e, int* __restrict__ tile_row0,
                            int* __restrict__ tile_cnt, int* __restrict__ tileCount) {
  __shared__ int totals[NE];
  __shared__ int bases[NE];
  int t = threadIdx.x;
  if (t < NE) {
    int run = 0;
    for (int b = 0; b < NB; ++b) run += blockCounts[t * NB + b];
    totals[t] = run;
  }
  __syncthreads();
  if (t == 0) {
    int base = 0, nt = 0;
    for (int e = 0; e < NE; ++e) {
      bases[e] = base;
      int tot = totals[e];
      for (int i = 0; i < tot; i += MT) {
        tile_e[nt] = e;
        tile_row0[nt] = base + i;
        tile_cnt[nt] = (tot - i < MT) ? (tot - i) : MT;
        ++nt;
      }
      base += tot;
    }
    *tileCount = nt;
  }
  __syncthreads();
  if (t < NE) {
    int run = bases[t];
    for (int b = 0; b < NB; ++b) {
      startEB[t * NB + b] = run;
      run += blockCounts[t * NB + b];
    }
  }
}

__global__ void place_kernel(const int* __restrict__ slot_e, const float* __restrict__ slot_w,
                             const int* __restrict__ startEB,
                             int* __restrict__ perm_token, float* __restrict__ perm_w,
                             int* __restrict__ inv) {
  __shared__ int se[256];
  __shared__ float sw[256];
  int b = blockIdx.x;
  for (int i = threadIdx.x; i < 256; i += 64) {
    se[i] = slot_e[b * 256 + i];
    sw[i] = slot_w[b * 256 + i];
  }
  __syncthreads();
  int e = threadIdx.x;
  if (e < NE) {
    int pos = startEB[e * NB + b];
    for (int i = 0; i < 256; ++i) {
      if (se[i] == e) {
        perm_token[pos] = (b * 256 + i) >> 3;
        perm_w[pos] = sw[i];
        inv[b * 256 + i] = pos;
        ++pos;
      }
    }
  }
}

// ---------------- 4-window 256x256 grouped GEMM machinery ----------------
// One window per (buf,kk) region: lgkm-drain + vmcnt(N) + single barrier, then two
// 16-MFMA sub-phases with free compiler scheduling. vmcnt(8) steady, 8/8/4/0 tail.

#define GUMM(AR, M_)                                                                   \
  acc[M_][0] = __builtin_amdgcn_mfma_f32_16x16x32_bf16(AR, b0, acc[M_][0], 0, 0, 0);   \
  acc[M_][1] = __builtin_amdgcn_mfma_f32_16x16x32_bf16(AR, b1, acc[M_][1], 0, 0, 0);   \
  acc[M_][2] = __builtin_amdgcn_mfma_f32_16x16x32_bf16(AR, b2, acc[M_][2], 0, 0, 0);   \
  acc[M_][3] = __builtin_amdgcn_mfma_f32_16x16x32_bf16(AR, b3, acc[M_][3], 0, 0, 0);

#define GWIN(BUF, KK, VM, S1, S2)                                                      \
  do {                                                                                 \
    asm volatile("s_waitcnt lgkmcnt(0)" ::: "memory");                                 \
    __builtin_amdgcn_sched_barrier(0);                                                 \
    asm volatile("s_waitcnt vmcnt(" #VM ")" ::: "memory");                             \
    __builtin_amdgcn_s_barrier();                                                      \
    const u16* Ap_ = &SA[BUF][KK][abase];                                              \
    const u16* Bp_ = &SB[BUF][KK][0];                                                  \
    bf16x8 a0_ = *(const bf16x8*)(Ap_);                                                \
    bf16x8 a1_ = *(const bf16x8*)(Ap_ + 512);                                          \
    bf16x8 a2_ = *(const bf16x8*)(Ap_ + 1024);                                         \
    bf16x8 a3_ = *(const bf16x8*)(Ap_ + 1536);                                         \
    bf16x8 b0 = *(const bf16x8*)(Bp_ + boff0);                                         \
    bf16x8 b1 = *(const bf16x8*)(Bp_ + boff1);                                         \
    bf16x8 b2 = *(const bf16x8*)(Bp_ + boff2);                                         \
    bf16x8 b3 = *(const bf16x8*)(Bp_ + boff3);                                         \
    S1;                                                                                \
    __builtin_amdgcn_s_setprio(1);                                                     \
    GUMM(a0_, 0) GUMM(a1_, 1) GUMM(a2_, 2) GUMM(a3_, 3)                                \
    __builtin_amdgcn_s_setprio(0);                                                     \
    bf16x8 c0_ = *(const bf16x8*)(Ap_ + 2048);                                         \
    bf16x8 c1_ = *(const bf16x8*)(Ap_ + 2560);                                         \
    bf16x8 c2_ = *(const bf16x8*)(Ap_ + 3072);                                         \
    bf16x8 c3_ = *(const bf16x8*)(Ap_ + 3584);                                         \
    S2;                                                                                \
    __builtin_amdgcn_s_setprio(1);                                                     \
    GUMM(c0_, 4) GUMM(c1_, 5) GUMM(c2_, 6) GUMM(c3_, 7)                                \
    __builtin_amdgcn_s_setprio(0);                                                     \
  } while (0)

// ---------------- gate_up GEMM: 256 slots x (128 gate + 128 up cols) ----------------
__global__ __launch_bounds__(512, 2) void gu_fast(
    const u16* __restrict__ xb, const u16* __restrict__ wgub,
    const int* __restrict__ perm_token,
    const int* __restrict__ tile_e, const int* __restrict__ tile_row0,
    const int* __restrict__ tile_cnt, const int* __restrict__ tileCount,
    u16* __restrict__ h_perm) {
  // XCD clustering: flat%8 = XCD; give each XCD a contiguous 36-tile chunk.
  int flat = blockIdx.x + blockIdx.y * 6;       // NWG = 6*288 = 1728, %8 == 0
  int xcd = flat & 7;
  int j = flat >> 3;                            // 0..215
  int tile = xcd * 36 + j / 6;
  int n0g = (j % 6) * 128;
  if (tile >= *tileCount) return;
  int e = tile_e[tile], row0 = tile_row0[tile], cnt = tile_cnt[tile];
  __shared__ __align__(16) u16 SA[2][2][8192];   // [buf][kk][256 rows x 32 K]
  __shared__ __align__(16) u16 SB[2][2][8192];   // rows 0-127 gate, 128-255 up
  __shared__ int toks[256];
  int tid = threadIdx.x;
  if (tid < 256) {
    int idx = row0 + tid;
    if (idx > NSLOT - 1) idx = NSLOT - 1;
    toks[tid] = perm_token[idx];
  }
  __syncthreads();
  int wave = tid >> 6, lane = tid & 63;
  int wr = wave >> 2, wc = wave & 3;
  int lr = lane & 15, lk = lane >> 4;
  int sr0 = tid >> 2;                       // rows 0..127 (+128 for 2nd load)
  int sc0 = (tid & 3) ^ ((tid >> 3) & 3);   // pre-swizzled K-chunk
  const u16* gA0 = xb + (size_t)toks[sr0] * HID + sc0 * 8;
  const u16* gA1 = xb + (size_t)toks[128 + sr0] * HID + sc0 * 8;
  const u16* wgb = wgub + (size_t)e * (2 * DFF) * HID;
  const u16* gB0 = wgb + (size_t)(n0g + sr0) * HID + sc0 * 8;          // gate row
  const u16* gB1 = wgb + (size_t)(DFF + n0g + sr0) * HID + sc0 * 8;    // up row
  int d0 = tid * 8, d1 = 4096 + tid * 8;    // linear LDS dests (u16 units)

  int slot8 = (lk ^ ((lr >> 1) & 3)) * 8;
  int abase = (wr * 128 + lr) * 32 + slot8;
  int boff0 = (wc * 32 + 0 * 16 + lr) * 32 + slot8;          // gate
  int boff1 = (wc * 32 + 1 * 16 + lr) * 32 + slot8;          // gate
  int boff2 = (128 + wc * 32 + 0 * 16 + lr) * 32 + slot8;    // up
  int boff3 = (128 + wc * 32 + 1 * 16 + lr) * 32 + slot8;    // up

  f32x4 acc[8][4];
  f32x4 zero = {0.f, 0.f, 0.f, 0.f};
#pragma unroll
  for (int m = 0; m < 8; ++m)
#pragma unroll
    for (int n = 0; n < 4; ++n) acc[m][n] = zero;

#define GU_SGA(BUF, KK, KT) do { \
    gload16(gA0 + (KT) + (KK) * 32, &SA[BUF][KK][d0]); \
    gload16(gA1 + (KT) + (KK) * 32, &SA[BUF][KK][d1]); } while (0)
#define GU_SGB(BUF, KK, KT) do { \
    gload16(gB0 + (KT) + (KK) * 32, &SB[BUF][KK][d0]); \
    gload16(gB1 + (KT) + (KK) * 32, &SB[BUF][KK][d1]); } while (0)

  // prologue: t0 full (buf0), t1.kk0 (buf1) = 12 loads in flight
  GU_SGA(0, 0, 0); GU_SGB(0, 0, 0);
  GU_SGA(0, 1, 0); GU_SGB(0, 1, 0);
  GU_SGA(1, 0, 64); GU_SGB(1, 0, 64);

  const int NKT = HID / 64;   // 32
  const int NI = NKT / 2;     // 16
  for (int it = 0; it < NI - 1; ++it) {
    int ktA = (2 * it + 1) * 64;
    int ktB = (2 * it + 2) * 64;
    int ktC = (2 * it + 3) * 64;
    GWIN(0, 0, 8, GU_SGA(1, 1, ktA), GU_SGB(1, 1, ktA));
    GWIN(0, 1, 8, GU_SGA(0, 0, ktB), GU_SGB(0, 0, ktB));
    GWIN(1, 0, 8, GU_SGA(0, 1, ktB), GU_SGB(0, 1, ktB));
    GWIN(1, 1, 8, GU_SGA(1, 0, ktC), GU_SGB(1, 0, ktC));
  }
  {
    int ktA = (2 * (NI - 1) + 1) * 64;
    GWIN(0, 0, 8, GU_SGA(1, 1, ktA), GU_SGB(1, 1, ktA));
    GWIN(0, 1, 8, (void)0, (void)0);
    GWIN(1, 0, 4, (void)0, (void)0);
    GWIN(1, 1, 0, (void)0, (void)0);
  }

  // epilogue: h = silu(g) * u ; acc[m][0,1]=gate cols, acc[m][2,3]=up cols
#pragma unroll
  for (int m = 0; m < 8; ++m)
#pragma unroll
    for (int i = 0; i < 4; ++i) {
      int row = wr * 128 + m * 16 + lk * 4 + i;
      if (row < cnt) {
#pragma unroll
        for (int nf = 0; nf < 2; ++nf) {
          int col = n0g + wc * 32 + nf * 16 + lr;
          float g = acc[m][nf][i], u = acc[m][nf + 2][i];
          float h = g / (1.f + __expf(-g)) * u;
          h_perm[(size_t)(row0 + row) * DFF + col] = f2bf(h);
        }
      }
    }
#undef GU_SGA
#undef GU_SGB
}

// ---------------- down GEMM: 256 slots x 256 hid cols -> yp (fp16) ----------------
__global__ __launch_bounds__(512, 2) void down_fast(
    const u16* __restrict__ h_perm, const u16* __restrict__ wdb,
    const float* __restrict__ perm_w,
    const int* __restrict__ tile_e, const int* __restrict__ tile_row0,
    const int* __restrict__ tile_cnt, const int* __restrict__ tileCount,
    _Float16* __restrict__ yp) {
  int flat = blockIdx.x + blockIdx.y * 8;       // NWG = 8*288 = 2304, %8 == 0
  int xcd = flat & 7;
  int j = flat >> 3;                            // 0..287
  int tile = xcd * 36 + j / 8;
  int n0 = (j % 8) * 256;
  if (tile >= *tileCount) return;
  int e = tile_e[tile], row0 = tile_row0[tile], cnt = tile_cnt[tile];
  __shared__ __align__(16) u16 SA[2][2][8192];
  __shared__ __align__(16) u16 SB[2][2][8192];
  __shared__ float wts[256];
  int tid = threadIdx.x;
  if (tid < 256) {
    int idx = row0 + tid;
    if (idx > NSLOT - 1) idx = NSLOT - 1;
    wts[tid] = perm_w[idx];
  }
  __syncthreads();
  int wave = tid >> 6, lane = tid & 63;
  int wr = wave >> 2, wc = wave & 3;
  int lr = lane & 15, lk = lane >> 4;
  int sr0 = tid >> 2;
  int sc0 = (tid & 3) ^ ((tid >> 3) & 3);
  int ia0 = row0 + sr0;       if (ia0 > NSLOT - 1) ia0 = NSLOT - 1;
  int ia1 = row0 + 128 + sr0; if (ia1 > NSLOT - 1) ia1 = NSLOT - 1;
  const u16* gA0 = h_perm + (size_t)ia0 * DFF + sc0 * 8;
  const u16* gA1 = h_perm + (size_t)ia1 * DFF + sc0 * 8;
  const u16* wb = wdb + (size_t)e * HID * DFF;
  const u16* gB0 = wb + (size_t)(n0 + sr0) * DFF + sc0 * 8;
  const u16* gB1 = wb + (size_t)(n0 + 128 + sr0) * DFF + sc0 * 8;
  int d0 = tid * 8, d1 = 4096 + tid * 8;

  int slot8 = (lk ^ ((lr >> 1) & 3)) * 8;
  int abase = (wr * 128 + lr) * 32 + slot8;
  int boff0 = (wc * 64 + 0 * 16 + lr) * 32 + slot8;
  int boff1 = (wc * 64 + 1 * 16 + lr) * 32 + slot8;
  int boff2 = (wc * 64 + 2 * 16 + lr) * 32 + slot8;
  int boff3 = (wc * 64 + 3 * 16 + lr) * 32 + slot8;

  f32x4 acc[8][4];
  f32x4 zero = {0.f, 0.f, 0.f, 0.f};
#pragma unroll
  for (int m = 0; m < 8; ++m)
#pragma unroll
    for (int n = 0; n < 4; ++n) acc[m][n] = zero;

#define DN_SGA(BUF, KK, KT) do { \
    gload16(gA0 + (KT) + (KK) * 32, &SA[BUF][KK][d0]); \
    gload16(gA1 + (KT) + (KK) * 32, &SA[BUF][KK][d1]); } while (0)
#define DN_SGB(BUF, KK, KT) do { \
    gload16(gB0 + (KT) + (KK) * 32, &SB[BUF][KK][d0]); \
    gload16(gB1 + (KT) + (KK) * 32, &SB[BUF][KK][d1]); } while (0)

  DN_SGA(0, 0, 0); DN_SGB(0, 0, 0);
  DN_SGA(0, 1, 0); DN_SGB(0, 1, 0);
  DN_SGA(1, 0, 64); DN_SGB(1, 0, 64);

  const int NKT = DFF / 64;   // 12
  const int NI = NKT / 2;     // 6
  for (int it = 0; it < NI - 1; ++it) {
    int ktA = (2 * it + 1) * 64;
    int ktB = (2 * it + 2) * 64;
    int ktC = (2 * it + 3) * 64;
    GWIN(0, 0, 8, DN_SGA(1, 1, ktA), DN_SGB(1, 1, ktA));
    GWIN(0, 1, 8, DN_SGA(0, 0, ktB), DN_SGB(0, 0, ktB));
    GWIN(1, 0, 8, DN_SGA(0, 1, ktB), DN_SGB(0, 1, ktB));
    GWIN(1, 1, 8, DN_SGA(1, 0, ktC), DN_SGB(1, 0, ktC));
  }
  {
    int ktA = (2 * (NI - 1) + 1) * 64;
    GWIN(0, 0, 8, DN_SGA(1, 1, ktA), DN_SGB(1, 1, ktA));
    GWIN(0, 1, 8, (void)0, (void)0);
    GWIN(1, 0, 4, (void)0, (void)0);
    GWIN(1, 1, 0, (void)0, (void)0);
  }

#pragma unroll
  for (int m = 0; m < 8; ++m)
#pragma unroll
    for (int i = 0; i < 4; ++i) {
      int row = wr * 128 + m * 16 + lk * 4 + i;
      if (row < cnt) {
        float wt = wts[row];
#pragma unroll
        for (int nf = 0; nf < 4; ++nf) {
          int col = n0 + wc * 64 + nf * 16 + lr;
          yp[(size_t)(row0 + row) * HID + col] = (_Float16)(acc[m][nf][i] * wt);
        }
      }
    }
#undef DN_SGA
#undef DN_SGB
}

// ---------------- per-token gather-reduce of 8 slots ----------------
__global__ void reduce_kernel(const _Float16* __restrict__ yp, const int* __restrict__ inv,
                              float* __restrict__ y) {
  int t = blockIdx.x;
  __shared__ int pos[8];
  if (threadIdx.x < 8) pos[threadIdx.x] = inv[t * 8 + threadIdx.x];
  __syncthreads();
  int c = threadIdx.x * 8;
  float s[8] = {0.f, 0.f, 0.f, 0.f, 0.f, 0.f, 0.f, 0.f};
#pragma unroll
  for (int j = 0; j < 8; ++j) {
    uint4 v = *reinterpret_cast<const uint4*>(yp + (size_t)pos[j] * HID + c);
    const u16* p = reinterpret_cast<const u16*>(&v);
#pragma unroll
    for (int k = 0; k < 8; ++k) {
      _Float16 h;
      u16 us = p[k];
      __builtin_memcpy(&h, &us, 2);
      s[k] += (float)h;
    }
  }
  float* yo = y + (size_t)t * HID + c;
  float4 o0 = {s[0], s[1], s[2], s[3]};
  float4 o1 = {s[4], s[5], s[6], s[7]};
  *reinterpret_cast<float4*>(yo) = o0;
  *reinterpret_cast<float4*>(yo + 4) = o1;
}

extern "C" void kernel_launch(void* const* d_in, const int* in_sizes, int n_in,
                              void* d_out, int out_size, void* d_ws, size_t ws_size,
                              hipStream_t stream) {
  const float* x = (const float*)d_in[0];
  const float* gw = (const float*)d_in[1];
  const float* wgu = (const float*)d_in[2];
  const float* wd = (const float*)d_in[3];
  const float* sim = (const float*)d_in[4];
  float* y = (float*)d_out;

  char* ws = (char*)d_ws;
  size_t off = 0;
  auto alloc = [&](size_t bytes) {
    char* p = ws + off;
    off += (bytes + 255) & ~(size_t)255;
    return p;
  };
  u16* xb = (u16*)alloc((size_t)NTOK * HID * 2);
  u16* h_perm = (u16*)alloc((size_t)NSLOT * DFF * 2);
  int* slot_e = (int*)alloc(NSLOT * 4);
  float* slot_w = (float*)alloc(NSLOT * 4);
  int* perm_token = (int*)alloc(NSLOT * 4);
  float* perm_w = (float*)alloc(NSLOT * 4);
  int* inv = (int*)alloc(NSLOT * 4);
  int* blockCounts = (int*)alloc(NE * NB * 4);
  int* startEB = (int*)alloc(NE * NB * 4);
  int* tile_e = (int*)alloc(MAX_TILES * 4);
  int* tile_row0 = (int*)alloc(MAX_TILES * 4);
  int* tile_cnt = (int*)alloc(MAX_TILES * 4);
  int* tileCount = (int*)alloc(4);

  // bf16 weights + fp16 per-slot down output (yp aliases wgu_b region)
  size_t wgu_elems = (size_t)NE * 2 * DFF * HID;
  size_t wd_elems = (size_t)NE * HID * DFF;
  size_t region_bytes = (size_t)NSLOT * HID * 2;  // yp (268MB) > wgu_b (201MB)
  u16* wd_b = (u16*)alloc(wd_elems * 2);
  char* region = alloc(region_bytes);
  u16* wgu_b = (u16*)region;
  _Float16* yp = (_Float16*)region;
  if (off > ws_size) return;  // insufficient workspace: fail loudly

  router_kernel<<<NTOK, 256, 0, stream>>>(x, gw, sim, slot_e, slot_w, xb);
  hist_kernel<<<NB, 256, 0, stream>>>(slot_e, blockCounts);
  scan_kernel<<<1, 64, 0, stream>>>(blockCounts, startEB, tile_e, tile_row0, tile_cnt, tileCount);
  place_kernel<<<NB, 64, 0, stream>>>(slot_e, slot_w, startEB, perm_token, perm_w, inv);

  convertf2b_kernel<<<4096, 256, 0, stream>>>(wgu, wgu_b, (int)(wgu_elems / 4));
  convertf2b_kernel<<<4096, 256, 0, stream>>>(wd, wd_b, (int)(wd_elems / 4));
  gu_fast<<<dim3(DFF / 128, MAX_TILES), 512, 0, stream>>>(
      xb, wgu_b, perm_token, tile_e, tile_row0, tile_cnt, tileCount, h_perm);
  down_fast<<<dim3(HID / 256, MAX_TILES), 512, 0, stream>>>(
      h_perm, wd_b, perm_w, tile_e, tile_row0, tile_cnt, tileCount, yp);
  reduce_kernel<<<NTOK, 256, 0, stream>>>(yp, inv, y);
}